// Round 7
// baseline (2647.002 us; speedup 1.0000x reference)
//
#include <hip/hip_runtime.h>

// Problem constants
constexpr int kE = 65536, kNTOT = 8192;
constexpr int GRID = 512;

// ---------------- threefry2x32 (JAX-exact, 20 rounds) ----------------
__host__ __device__ __forceinline__ void tf_round(unsigned& x0, unsigned& x1, int r) {
  x0 += x1;
  x1 = (x1 << r) | (x1 >> (32 - r));
  x1 ^= x0;
}
__host__ __device__ __forceinline__ void tf2x32(unsigned k0, unsigned k1,
                                                unsigned& x0, unsigned& x1) {
  unsigned ks2 = k0 ^ k1 ^ 0x1BD11BDAu;
  x0 += k0; x1 += k1;
  tf_round(x0,x1,13); tf_round(x0,x1,15); tf_round(x0,x1,26); tf_round(x0,x1,6);
  x0 += k1; x1 += ks2 + 1u;
  tf_round(x0,x1,17); tf_round(x0,x1,29); tf_round(x0,x1,16); tf_round(x0,x1,24);
  x0 += ks2; x1 += k0 + 2u;
  tf_round(x0,x1,13); tf_round(x0,x1,15); tf_round(x0,x1,26); tf_round(x0,x1,6);
  x0 += k0; x1 += k1 + 3u;
  tf_round(x0,x1,17); tf_round(x0,x1,29); tf_round(x0,x1,16); tf_round(x0,x1,24);
  x0 += k1; x1 += ks2 + 4u;
  tf_round(x0,x1,13); tf_round(x0,x1,15); tf_round(x0,x1,26); tf_round(x0,x1,6);
  x0 += ks2; x1 += k0 + 5u;
}

// bits -> N(0,1), replicating jax.random.normal f32 path (partitionable threefry)
__device__ __forceinline__ float bits_to_normal(unsigned bits) {
  float f = __uint_as_float((bits >> 9) | 0x3f800000u) - 1.0f;  // [0,1)
  const float LO = -0.99999994f;
  float u = fmaf(f, 2.0f, LO);
  u = fmaxf(u, LO);
  float w = -log1pf(-u * u);
  float p;
  if (w < 5.0f) {
    w -= 2.5f;
    p = 2.81022636e-08f;
    p = fmaf(p, w, 3.43273939e-07f);
    p = fmaf(p, w, -3.5233877e-06f);
    p = fmaf(p, w, -4.39150654e-06f);
    p = fmaf(p, w, 0.00021858087f);
    p = fmaf(p, w, -0.00125372503f);
    p = fmaf(p, w, -0.00417768164f);
    p = fmaf(p, w, 0.246640727f);
    p = fmaf(p, w, 1.50140941f);
  } else {
    w = sqrtf(w) - 3.0f;
    p = -0.000200214257f;
    p = fmaf(p, w, 0.000100950558f);
    p = fmaf(p, w, 0.00134934322f);
    p = fmaf(p, w, -0.00367342844f);
    p = fmaf(p, w, 0.00573950773f);
    p = fmaf(p, w, -0.0076224613f);
    p = fmaf(p, w, 0.00943887047f);
    p = fmaf(p, w, 1.00167406f);
    p = fmaf(p, w, 2.83297682f);
  }
  return 1.41421356f * (p * u);
}

// ---------------- grid barrier (monotonic counter, device-scope) ----------------
__device__ __forceinline__ void gsync(int* bar, int target) {
  __threadfence();            // release
  __syncthreads();
  if (threadIdx.x == 0) {
    atomicAdd(bar, 1);
    while (__hip_atomic_load(bar, __ATOMIC_RELAXED, __HIP_MEMORY_SCOPE_AGENT) < target) {
      __builtin_amdgcn_s_sleep(2);
    }
  }
  __syncthreads();
  __threadfence();            // acquire
}

__device__ __forceinline__ float redmax32(float v) {
#pragma unroll
  for (int o = 16; o > 0; o >>= 1) v = fmaxf(v, __shfl_xor(v, o));
  return v;
}
__device__ __forceinline__ float redsum32(float v) {
#pragma unroll
  for (int o = 16; o > 0; o >>= 1) v += __shfl_xor(v, o);
  return v;
}

// ---------------- msg GEMM phase: msg[i] = relu(x[srcs[i]]@Wm + ef[perm[i]]@We) -----
template <int KX>
__device__ __forceinline__ void msg_phase(float* smb, int gid, int t,
    const float* xR, const float* efR, const int* srcsR, const int* permR, float* msgR,
    const float* xP, const float* efP, const int* srcsP, const int* permP, float* msgP,
    const float* Wm, const float* We) {
  constexpr int KT = KX + 16;
  typedef float Row68[68];
  Row68* sA = (Row68*)smb;
  Row68* sW = (Row68*)(smb + KT * 68);
#pragma unroll
  for (int idx = 0; idx < KT * 64 / 1024; ++idx) {
    int q = (idx * 256 + t) * 4;
    int k = q >> 6, j = q & 63;
    const float* sp = (k < KX) ? (Wm + k * 64 + j) : (We + (k - KX) * 64 + j);
    float4 v = *reinterpret_cast<const float4*>(sp);
    sW[k][j] = v.x; sW[k][j + 1] = v.y; sW[k][j + 2] = v.z; sW[k][j + 3] = v.w;
  }
  for (int rep = 0; rep < 4; ++rep) {
    int tl = gid * 4 + rep;            // 0..2047
    bool isP = tl >= 1024;
    const float* x = isP ? xP : xR;
    const float* ef = isP ? efP : efR;
    const int* srcs = isP ? srcsP : srcsR;
    const int* perm = isP ? permP : permR;
    float* msg = isP ? msgP : msgR;
    int i0 = (tl & 1023) * 64;
    __syncthreads();
#pragma unroll
    for (int idx = 0; idx < KT * 64 / 1024; ++idx) {
      int q = t * 4 + idx * 1024;
      int r = q / KT, k = q % KT;      // k 4-aligned (KT % 4 == 0)
      const float* rptr = (k < KX) ? (x + (size_t)srcs[i0 + r] * KX + k)
                                   : (ef + (size_t)perm[i0 + r] * 16 + (k - KX));
      float4 v = *reinterpret_cast<const float4*>(rptr);
      sA[k][r] = v.x; sA[k + 1][r] = v.y; sA[k + 2][r] = v.z; sA[k + 3][r] = v.w;
    }
    __syncthreads();
    int tn = (t & 15) * 4, tj = (t >> 4) * 4;
    float acc[4][4] = {};
#pragma unroll 8
    for (int k = 0; k < KT; ++k) {
      float4 a = *reinterpret_cast<const float4*>(&sA[k][tn]);
      float4 b = *reinterpret_cast<const float4*>(&sW[k][tj]);
      acc[0][0] = fmaf(a.x, b.x, acc[0][0]); acc[0][1] = fmaf(a.x, b.y, acc[0][1]);
      acc[0][2] = fmaf(a.x, b.z, acc[0][2]); acc[0][3] = fmaf(a.x, b.w, acc[0][3]);
      acc[1][0] = fmaf(a.y, b.x, acc[1][0]); acc[1][1] = fmaf(a.y, b.y, acc[1][1]);
      acc[1][2] = fmaf(a.y, b.z, acc[1][2]); acc[1][3] = fmaf(a.y, b.w, acc[1][3]);
      acc[2][0] = fmaf(a.z, b.x, acc[2][0]); acc[2][1] = fmaf(a.z, b.y, acc[2][1]);
      acc[2][2] = fmaf(a.z, b.z, acc[2][2]); acc[2][3] = fmaf(a.z, b.w, acc[2][3]);
      acc[3][0] = fmaf(a.w, b.x, acc[3][0]); acc[3][1] = fmaf(a.w, b.y, acc[3][1]);
      acc[3][2] = fmaf(a.w, b.z, acc[3][2]); acc[3][3] = fmaf(a.w, b.w, acc[3][3]);
    }
#pragma unroll
    for (int i = 0; i < 4; ++i) {
      float4 o;
      o.x = fmaxf(acc[i][0], 0.f); o.y = fmaxf(acc[i][1], 0.f);
      o.z = fmaxf(acc[i][2], 0.f); o.w = fmaxf(acc[i][3], 0.f);
      *reinterpret_cast<float4*>(&msg[(size_t)(i0 + tn + i) * 64 + tj]) = o;
    }
  }
}

// ---------------- agg phase: segment sums, 16384 wave-tasks over 2048 waves ----------
__device__ __forceinline__ void agg_phase(int gid, int t,
    const float* msgR, const int* rpR, float* aggR,
    const float* msgP, const int* rpP, float* aggP) {
  int lane = t & 63;
  int wave = gid * 4 + (t >> 6);
  for (int k = 0; k < 8; ++k) {
    int idx = wave * 8 + k;            // 0..16383
    const float* msg = (idx < kNTOT) ? msgR : msgP;
    const int* rp = (idx < kNTOT) ? rpR : rpP;
    float* agg = (idx < kNTOT) ? aggR : aggP;
    int d = idx & (kNTOT - 1);
    int s = rp[d], e = rp[d + 1];
    float acc = 0.f;
    for (int i = s; i < e; ++i) acc += msg[(size_t)i * 64 + lane];
    agg[(size_t)d * 64 + lane] = acc;
  }
}

// =============================== THE MEGA KERNEL ===============================
__global__ __launch_bounds__(256, 2) void mega_kern(
    const float* __restrict__ x_r, const int* __restrict__ ei_r, const float* __restrict__ ef_r,
    const float* __restrict__ x_p, const int* __restrict__ ei_p, const float* __restrict__ ef_p,
    const float* __restrict__ g1_Ws, const float* __restrict__ g1_Wm,
    const float* __restrict__ g1_We, const float* __restrict__ g1_b,
    const float* __restrict__ g2_Ws, const float* __restrict__ g2_Wm,
    const float* __restrict__ g2_We, const float* __restrict__ g2_b,
    const float* __restrict__ W1, const float* __restrict__ b1,
    const float* __restrict__ W2, const float* __restrict__ b2,
    float* __restrict__ out,
    float* h_r, float* h_p, float* Mhat, float* Msoft,
    float* rfr, float* rfp, float* u_r, float* u_p,
    float* agg_r, float* agg_p, float* msg_r, float* msg_p,
    int* bar, int* cnt_r, int* cnt_p, int* off_r, int* off_p,
    int* rp_r, int* rp_p, int* perm_r, int* perm_p, int* srcs_r, int* srcs_p,
    unsigned fk0a, unsigned fk1a, unsigned fk0b, unsigned fk1b,
    unsigned fk0c, unsigned fk1c) {
  __shared__ __align__(16) float sm[13312];   // 52 KB, max over phases (node2u)
  const int gid = blockIdx.x, t = threadIdx.x;
  const int gtid = (gid << 8) + t;            // 0..131071
  int ph = 0;
  unsigned fks0[3] = {fk0a, fk0b, fk0c};
  unsigned fks1[3] = {fk1a, fk1b, fk1c};

  // ---- P1: histogram of dst ----
  {
    const int* ei = (gtid < kE) ? ei_r : ei_p;
    int* cnt = (gtid < kE) ? cnt_r : cnt_p;
    int e = gtid & (kE - 1);
    atomicAdd(&cnt[ei[kE + e]], 1);
  }
  gsync(bar, (++ph) * GRID);

  // ---- P2: exclusive scan (blocks 0,1) ----
  if (gid < 2) {
    const int* cnt = gid ? cnt_p : cnt_r;
    int* rp = gid ? rp_p : rp_r;
    int* off = gid ? off_p : off_r;
    int* wsum = (int*)sm;
    int base = t * 32;
    int v[32];
    int sum = 0;
#pragma unroll
    for (int i = 0; i < 32; ++i) { v[i] = cnt[base + i]; sum += v[i]; }
    int lane = t & 63, w = t >> 6;
    int incl = sum;
#pragma unroll
    for (int o = 1; o < 64; o <<= 1) { int y = __shfl_up(incl, o); if (lane >= o) incl += y; }
    if (lane == 63) wsum[w] = incl;
    __syncthreads();
    int woff = 0;
#pragma unroll
    for (int i = 0; i < 4; ++i) if (i < w) woff += wsum[i];
    int running = woff + incl - sum;
#pragma unroll
    for (int i = 0; i < 32; ++i) { rp[base + i] = running; off[base + i] = running; running += v[i]; }
    if (t == 0) rp[kNTOT] = kE;
  }
  gsync(bar, (++ph) * GRID);

  // ---- P3: scatter into CSR order ----
  {
    const int* ei = (gtid < kE) ? ei_r : ei_p;
    int* off = (gtid < kE) ? off_r : off_p;
    int* perm = (gtid < kE) ? perm_r : perm_p;
    int* srcs = (gtid < kE) ? srcs_r : srcs_p;
    int e = gtid & (kE - 1);
    int dst = ei[kE + e];
    int pos = atomicAdd(&off[dst], 1);
    perm[pos] = e;
    srcs[pos] = ei[e];
  }
  gsync(bar, (++ph) * GRID);

  // ---- P4: gnn1 msg GEMM ----
  msg_phase<64>(sm, gid, t, x_r, ef_r, srcs_r, perm_r, msg_r,
                x_p, ef_p, srcs_p, perm_p, msg_p, g1_Wm, g1_We);
  gsync(bar, (++ph) * GRID);

  // ---- P5: agg ----
  agg_phase(gid, t, msg_r, rp_r, agg_r, msg_p, rp_p, agg_p);
  gsync(bar, (++ph) * GRID);

  // ---- P6: node1 GEMM: h = relu(x@Ws + agg + b) (256 blocks) ----
  if (gid < 256) {
    typedef float Row68[68];
    Row68* sX = (Row68*)sm;
    Row68* sW = (Row68*)(sm + 64 * 68);
    bool isP = gid >= 128;
    const float* x = isP ? x_p : x_r;
    const float* agg = isP ? agg_p : agg_r;
    float* h = isP ? h_p : h_r;
    int n0 = (gid & 127) * 64;
#pragma unroll
    for (int idx = 0; idx < 4; ++idx) {
      int q = t * 4 + idx * 1024;
      int k = q >> 6, j = q & 63;
      float4 wv = *reinterpret_cast<const float4*>(g1_Ws + q);
      sW[k][j] = wv.x; sW[k][j + 1] = wv.y; sW[k][j + 2] = wv.z; sW[k][j + 3] = wv.w;
      float4 v = *reinterpret_cast<const float4*>(x + (size_t)n0 * 64 + q);
      sX[j + 0][k] = v.x; sX[j + 1][k] = v.y; sX[j + 2][k] = v.z; sX[j + 3][k] = v.w;
    }
    __syncthreads();
    int tn = (t & 15) * 4, tj = (t >> 4) * 4;
    float acc[4][4] = {};
#pragma unroll 8
    for (int k = 0; k < 64; ++k) {
      float4 a = *reinterpret_cast<const float4*>(&sX[k][tn]);
      float4 b = *reinterpret_cast<const float4*>(&sW[k][tj]);
      acc[0][0] = fmaf(a.x, b.x, acc[0][0]); acc[0][1] = fmaf(a.x, b.y, acc[0][1]);
      acc[0][2] = fmaf(a.x, b.z, acc[0][2]); acc[0][3] = fmaf(a.x, b.w, acc[0][3]);
      acc[1][0] = fmaf(a.y, b.x, acc[1][0]); acc[1][1] = fmaf(a.y, b.y, acc[1][1]);
      acc[1][2] = fmaf(a.y, b.z, acc[1][2]); acc[1][3] = fmaf(a.y, b.w, acc[1][3]);
      acc[2][0] = fmaf(a.z, b.x, acc[2][0]); acc[2][1] = fmaf(a.z, b.y, acc[2][1]);
      acc[2][2] = fmaf(a.z, b.z, acc[2][2]); acc[2][3] = fmaf(a.z, b.w, acc[2][3]);
      acc[3][0] = fmaf(a.w, b.x, acc[3][0]); acc[3][1] = fmaf(a.w, b.y, acc[3][1]);
      acc[3][2] = fmaf(a.w, b.z, acc[3][2]); acc[3][3] = fmaf(a.w, b.w, acc[3][3]);
    }
    float4 bv = *reinterpret_cast<const float4*>(g1_b + tj);
#pragma unroll
    for (int i = 0; i < 4; ++i) {
      int n = n0 + tn + i;
      float4 g = *reinterpret_cast<const float4*>(agg + (size_t)n * 64 + tj);
      float4 o;
      o.x = fmaxf(acc[i][0] + g.x + bv.x, 0.f);
      o.y = fmaxf(acc[i][1] + g.y + bv.y, 0.f);
      o.z = fmaxf(acc[i][2] + g.z + bv.z, 0.f);
      o.w = fmaxf(acc[i][3] + g.w + bv.w, 0.f);
      *reinterpret_cast<float4*>(&h[(size_t)n * 64 + tj]) = o;
    }
  }
  gsync(bar, (++ph) * GRID);

  // ---- P7: Mhat tile + fused softmax (-> Msoft, M0 out) + RNG(it=0) ----
  {
    {
      unsigned f0 = fks0[0], f1 = fks1[0];
#pragma unroll
      for (int q = 0; q < 2; ++q) {
        unsigned i = (unsigned)gtid + (unsigned)q * 131072u;
        unsigned a0 = 0u, a1 = i;
        tf2x32(f0, f1, a0, a1);
        rfr[i] = bits_to_normal(a0 ^ a1);
      }
    }
    typedef float Row66[66];
    Row66* hr = (Row66*)sm;             // 16 rows
    Row66* hp = (Row66*)(sm + 16 * 66); // 128 rows
    int b = gid >> 3, r0 = (gid & 7) * 16;
    const float* hrG = h_r + ((size_t)(b * 128 + r0)) * 64;
    {
      int q = t * 4; int r = q >> 6, d = q & 63;
      float4 v = *reinterpret_cast<const float4*>(hrG + q);
      hr[r][d] = v.x; hr[r][d + 1] = v.y; hr[r][d + 2] = v.z; hr[r][d + 3] = v.w;
    }
    const float* hpG = h_p + (size_t)b * 128 * 64;
#pragma unroll
    for (int rep = 0; rep < 8; ++rep) {
      int q = (rep * 256 + t) * 4; int p = q >> 6, d = q & 63;
      float4 v = *reinterpret_cast<const float4*>(hpG + q);
      hp[p][d] = v.x; hp[p][d + 1] = v.y; hp[p][d + 2] = v.z; hp[p][d + 3] = v.w;
    }
    __syncthreads();
    int tx = t & 31, ty = t >> 5;
    float acc[2][4] = {};
    for (int d = 0; d < 64; ++d) {
      float a0 = hr[ty][d], a1 = hr[ty + 8][d];
      float q0 = hp[tx][d], q1 = hp[tx + 32][d], q2 = hp[tx + 64][d], q3 = hp[tx + 96][d];
      acc[0][0] = fmaf(a0, q0, acc[0][0]); acc[0][1] = fmaf(a0, q1, acc[0][1]);
      acc[0][2] = fmaf(a0, q2, acc[0][2]); acc[0][3] = fmaf(a0, q3, acc[0][3]);
      acc[1][0] = fmaf(a1, q0, acc[1][0]); acc[1][1] = fmaf(a1, q1, acc[1][1]);
      acc[1][2] = fmaf(a1, q2, acc[1][2]); acc[1][3] = fmaf(a1, q3, acc[1][3]);
    }
#pragma unroll
    for (int ii = 0; ii < 2; ++ii) {
      int r = r0 + ty + 8 * ii;
      float* mrow = Mhat + ((size_t)(b * 128 + r)) * 128;
      mrow[tx] = acc[ii][0]; mrow[tx + 32] = acc[ii][1];
      mrow[tx + 64] = acc[ii][2]; mrow[tx + 96] = acc[ii][3];
      float mx = redmax32(fmaxf(fmaxf(acc[ii][0], acc[ii][1]), fmaxf(acc[ii][2], acc[ii][3])));
      float e0 = __expf(acc[ii][0] - mx), e1 = __expf(acc[ii][1] - mx);
      float e2 = __expf(acc[ii][2] - mx), e3 = __expf(acc[ii][3] - mx);
      float inv = 1.0f / redsum32(e0 + e1 + e2 + e3);
      float* srow = Msoft + ((size_t)(b * 128 + r)) * 128;
      srow[tx] = e0 * inv; srow[tx + 32] = e1 * inv;
      srow[tx + 64] = e2 * inv; srow[tx + 96] = e3 * inv;
      float* orow = out + ((size_t)(b * 128 + r)) * 128;   // M_0
      orow[tx] = e0 * inv; orow[tx + 32] = e1 * inv;
      orow[tx + 64] = e2 * inv; orow[tx + 96] = e3 * inv;
    }
  }
  gsync(bar, (++ph) * GRID);

  // ================= iteration loop =================
  for (int it = 0; it < 3; ++it) {
    // ---- A: rfp[b,p,i] = sum_r Msoft[b,r,p] * rfr[b,r,i] ----
    {
      typedef float Row36[36];
      Row36* rr = (Row36*)sm;
      int b = gid >> 3, p0 = (gid & 7) * 16;
      const float* rfG = rfr + (size_t)b * 4096;
#pragma unroll
      for (int rep = 0; rep < 4; ++rep) {
        int q = (rep * 256 + t) * 4; int r = q >> 5, i = q & 31;
        float4 v = *reinterpret_cast<const float4*>(rfG + q);
        rr[r][i] = v.x; rr[r][i + 1] = v.y; rr[r][i + 2] = v.z; rr[r][i + 3] = v.w;
      }
      __syncthreads();
      int pl = t & 15, ih = (t >> 4) * 2;
      int p = p0 + pl;
      const float* Mcol = Msoft + (size_t)b * 16384 + p;
      float a0 = 0.f, a1 = 0.f;
#pragma unroll 8
      for (int r = 0; r < 128; ++r) {
        float m = Mcol[(size_t)r * 128];
        a0 = fmaf(m, rr[r][ih], a0);
        a1 = fmaf(m, rr[r][ih + 1], a1);
      }
      float* dst = rfp + ((size_t)(b * 128 + p)) * 32 + ih;
      dst[0] = a0; dst[1] = a1;
      __syncthreads();   // protect rr before next phase reuses sm
    }
    gsync(bar, (++ph) * GRID);

    // ---- B: gnn2 msg GEMM ----
    msg_phase<32>(sm, gid, t, rfr, ef_r, srcs_r, perm_r, msg_r,
                  rfp, ef_p, srcs_p, perm_p, msg_p, g2_Wm, g2_We);
    gsync(bar, (++ph) * GRID);

    // ---- C: agg ----
    agg_phase(gid, t, msg_r, rp_r, agg_r, msg_p, rp_p, agg_p);
    gsync(bar, (++ph) * GRID);

    // ---- D: node2u: o = relu(rf@Ws2 + agg + g2b); u = o@W1 (+b1 for r) ----
    if (gid < 256) {
      typedef float Row68[68];
      Row68* sRF = (Row68*)sm;               // 32
      Row68* sW2 = (Row68*)(sm + 32 * 68);   // 32
      Row68* sW1 = (Row68*)(sm + 64 * 68);   // 64
      Row68* sO  = (Row68*)(sm + 128 * 68);  // 64
      bool isP = gid >= 128;
      const float* rf = isP ? rfp : rfr;
      const float* agg = isP ? agg_p : agg_r;
      float* u = isP ? u_p : u_r;
      int n0 = (gid & 127) * 64;
#pragma unroll
      for (int idx = 0; idx < 4; ++idx) {
        int q = t * 4 + idx * 1024;
        float4 wv = *reinterpret_cast<const float4*>(W1 + q);
        sW1[q >> 6][q & 63] = wv.x; sW1[q >> 6][(q & 63) + 1] = wv.y;
        sW1[q >> 6][(q & 63) + 2] = wv.z; sW1[q >> 6][(q & 63) + 3] = wv.w;
      }
#pragma unroll
      for (int idx = 0; idx < 2; ++idx) {
        int q = t * 4 + idx * 1024;
        // g2_Ws is [32][64] row-major: row = q>>6, col = q&63  (R6 bug: used >>5/&31)
        float4 wv = *reinterpret_cast<const float4*>(g2_Ws + q);
        sW2[q >> 6][q & 63] = wv.x; sW2[q >> 6][(q & 63) + 1] = wv.y;
        sW2[q >> 6][(q & 63) + 2] = wv.z; sW2[q >> 6][(q & 63) + 3] = wv.w;
        int r = q >> 5, kk = q & 31;
        float4 v = *reinterpret_cast<const float4*>(rf + (size_t)(n0 + r) * 32 + kk);
        sRF[kk][r] = v.x; sRF[kk + 1][r] = v.y; sRF[kk + 2][r] = v.z; sRF[kk + 3][r] = v.w;
      }
      __syncthreads();
      int tn = (t & 15) * 4, tj = (t >> 4) * 4;
      float acc[4][4] = {};
#pragma unroll 8
      for (int k = 0; k < 32; ++k) {
        float4 a = *reinterpret_cast<const float4*>(&sRF[k][tn]);
        float4 b = *reinterpret_cast<const float4*>(&sW2[k][tj]);
        acc[0][0] = fmaf(a.x, b.x, acc[0][0]); acc[0][1] = fmaf(a.x, b.y, acc[0][1]);
        acc[0][2] = fmaf(a.x, b.z, acc[0][2]); acc[0][3] = fmaf(a.x, b.w, acc[0][3]);
        acc[1][0] = fmaf(a.y, b.x, acc[1][0]); acc[1][1] = fmaf(a.y, b.y, acc[1][1]);
        acc[1][2] = fmaf(a.y, b.z, acc[1][2]); acc[1][3] = fmaf(a.y, b.w, acc[1][3]);
        acc[2][0] = fmaf(a.z, b.x, acc[2][0]); acc[2][1] = fmaf(a.z, b.y, acc[2][1]);
        acc[2][2] = fmaf(a.z, b.z, acc[2][2]); acc[2][3] = fmaf(a.z, b.w, acc[2][3]);
        acc[3][0] = fmaf(a.w, b.x, acc[3][0]); acc[3][1] = fmaf(a.w, b.y, acc[3][1]);
        acc[3][2] = fmaf(a.w, b.z, acc[3][2]); acc[3][3] = fmaf(a.w, b.w, acc[3][3]);
      }
      float4 bg = *reinterpret_cast<const float4*>(g2_b + tj);
#pragma unroll
      for (int i = 0; i < 4; ++i) {
        int n = n0 + tn + i;
        float4 g = *reinterpret_cast<const float4*>(agg + (size_t)n * 64 + tj);
        sO[tj + 0][tn + i] = fmaxf(acc[i][0] + g.x + bg.x, 0.f);
        sO[tj + 1][tn + i] = fmaxf(acc[i][1] + g.y + bg.y, 0.f);
        sO[tj + 2][tn + i] = fmaxf(acc[i][2] + g.z + bg.z, 0.f);
        sO[tj + 3][tn + i] = fmaxf(acc[i][3] + g.w + bg.w, 0.f);
      }
      __syncthreads();
      float acc2[4][4] = {};
#pragma unroll 8
      for (int k = 0; k < 64; ++k) {
        float4 a = *reinterpret_cast<const float4*>(&sO[k][tn]);
        float4 b = *reinterpret_cast<const float4*>(&sW1[k][tj]);
        acc2[0][0] = fmaf(a.x, b.x, acc2[0][0]); acc2[0][1] = fmaf(a.x, b.y, acc2[0][1]);
        acc2[0][2] = fmaf(a.x, b.z, acc2[0][2]); acc2[0][3] = fmaf(a.x, b.w, acc2[0][3]);
        acc2[1][0] = fmaf(a.y, b.x, acc2[1][0]); acc2[1][1] = fmaf(a.y, b.y, acc2[1][1]);
        acc2[1][2] = fmaf(a.y, b.z, acc2[1][2]); acc2[1][3] = fmaf(a.y, b.w, acc2[1][3]);
        acc2[2][0] = fmaf(a.z, b.x, acc2[2][0]); acc2[2][1] = fmaf(a.z, b.y, acc2[2][1]);
        acc2[2][2] = fmaf(a.z, b.z, acc2[2][2]); acc2[2][3] = fmaf(a.z, b.w, acc2[2][3]);
        acc2[3][0] = fmaf(a.w, b.x, acc2[3][0]); acc2[3][1] = fmaf(a.w, b.y, acc2[3][1]);
        acc2[3][2] = fmaf(a.w, b.z, acc2[3][2]); acc2[3][3] = fmaf(a.w, b.w, acc2[3][3]);
      }
      float4 b1v = make_float4(0.f, 0.f, 0.f, 0.f);
      if (!isP) b1v = *reinterpret_cast<const float4*>(b1 + tj);
#pragma unroll
      for (int i = 0; i < 4; ++i) {
        int n = n0 + tn + i;
        float4 o;
        o.x = acc2[i][0] + b1v.x; o.y = acc2[i][1] + b1v.y;
        o.z = acc2[i][2] + b1v.z; o.w = acc2[i][3] + b1v.w;
        *reinterpret_cast<float4*>(&u[(size_t)n * 64 + tj]) = o;
      }
    }
    gsync(bar, (++ph) * GRID);

    // ---- E: upd + fused softmax (+RNG for next iter / final output) ----
    {
      typedef float Row66[66];
      Row66* sur = (Row66*)sm;               // 16
      Row66* sup = (Row66*)(sm + 16 * 66);   // 128
      float* sw2 = sm + 144 * 66;            // 64
      int b = gid >> 3, r0 = (gid & 7) * 16;
      const float* urG = u_r + ((size_t)(b * 128 + r0)) * 64;
      {
        int q = t * 4; int r = q >> 6, d = q & 63;
        float4 v = *reinterpret_cast<const float4*>(urG + q);
        sur[r][d] = v.x; sur[r][d + 1] = v.y; sur[r][d + 2] = v.z; sur[r][d + 3] = v.w;
      }
      const float* upG = u_p + (size_t)b * 128 * 64;
#pragma unroll
      for (int rep = 0; rep < 8; ++rep) {
        int q = (rep * 256 + t) * 4; int p = q >> 6, d = q & 63;
        float4 v = *reinterpret_cast<const float4*>(upG + q);
        sup[p][d] = v.x; sup[p][d + 1] = v.y; sup[p][d + 2] = v.z; sup[p][d + 3] = v.w;
      }
      if (t < 64) sw2[t] = W2[t];
      __syncthreads();
      int tx = t & 31, ty = t >> 5;
      float acc[2][4] = {};
      for (int j = 0; j < 64; ++j) {
        float w2v = sw2[j];
        float a0 = sur[ty][j], a1 = sur[ty + 8][j];
        float q0 = sup[tx][j], q1 = sup[tx + 32][j], q2 = sup[tx + 64][j], q3 = sup[tx + 96][j];
        acc[0][0] = fmaf(fmaxf(a0 - q0, 0.f), w2v, acc[0][0]);
        acc[0][1] = fmaf(fmaxf(a0 - q1, 0.f), w2v, acc[0][1]);
        acc[0][2] = fmaf(fmaxf(a0 - q2, 0.f), w2v, acc[0][2]);
        acc[0][3] = fmaf(fmaxf(a0 - q3, 0.f), w2v, acc[0][3]);
        acc[1][0] = fmaf(fmaxf(a1 - q0, 0.f), w2v, acc[1][0]);
        acc[1][1] = fmaf(fmaxf(a1 - q1, 0.f), w2v, acc[1][1]);
        acc[1][2] = fmaf(fmaxf(a1 - q2, 0.f), w2v, acc[1][2]);
        acc[1][3] = fmaf(fmaxf(a1 - q3, 0.f), w2v, acc[1][3]);
      }
      float b2v = b2[0];
#pragma unroll
      for (int ii = 0; ii < 2; ++ii) {
        int r = r0 + ty + 8 * ii;
        float* mrow = Mhat + ((size_t)(b * 128 + r)) * 128;
        float m0 = mrow[tx] + acc[ii][0] + b2v;
        float m1 = mrow[tx + 32] + acc[ii][1] + b2v;
        float m2 = mrow[tx + 64] + acc[ii][2] + b2v;
        float m3 = mrow[tx + 96] + acc[ii][3] + b2v;
        if (it < 2) {   // Mhat needed again only by next upd (same block)
          mrow[tx] = m0; mrow[tx + 32] = m1; mrow[tx + 64] = m2; mrow[tx + 96] = m3;
        }
        float mx = redmax32(fmaxf(fmaxf(m0, m1), fmaxf(m2, m3)));
        float e0 = __expf(m0 - mx), e1 = __expf(m1 - mx);
        float e2 = __expf(m2 - mx), e3 = __expf(m3 - mx);
        float inv = 1.0f / redsum32(e0 + e1 + e2 + e3);
        float* srow = ((it == 2) ? (out + 1048576) : Msoft) + ((size_t)(b * 128 + r)) * 128;
        srow[tx] = e0 * inv; srow[tx + 32] = e1 * inv;
        srow[tx + 64] = e2 * inv; srow[tx + 96] = e3 * inv;
      }
      if (it < 2) {
        unsigned f0 = fks0[it + 1], f1 = fks1[it + 1];
#pragma unroll
        for (int q = 0; q < 2; ++q) {
          unsigned i = (unsigned)gtid + (unsigned)q * 131072u;
          unsigned a0 = 0u, a1 = i;
          tf2x32(f0, f1, a0, a1);
          rfr[i] = bits_to_normal(a0 ^ a1);
        }
      }
    }
    if (it < 2) gsync(bar, (++ph) * GRID);
  }
}

extern "C" void kernel_launch(void* const* d_in, const int* in_sizes, int n_in,
                              void* d_out, int out_size, void* d_ws, size_t ws_size,
                              hipStream_t stream) {
  (void)in_sizes; (void)n_in; (void)out_size; (void)ws_size;
  const float* x_r  = (const float*)d_in[0];
  const int*   ei_r = (const int*)d_in[1];
  const float* ef_r = (const float*)d_in[2];
  const float* x_p  = (const float*)d_in[3];
  const int*   ei_p = (const int*)d_in[4];
  const float* ef_p = (const float*)d_in[5];
  const float* g1_Ws = (const float*)d_in[8];
  const float* g1_Wm = (const float*)d_in[9];
  const float* g1_We = (const float*)d_in[10];
  const float* g1_b  = (const float*)d_in[11];
  const float* g2_Ws = (const float*)d_in[12];
  const float* g2_Wm = (const float*)d_in[13];
  const float* g2_We = (const float*)d_in[14];
  const float* g2_b  = (const float*)d_in[15];
  const float* W1 = (const float*)d_in[16];
  const float* b1 = (const float*)d_in[17];
  const float* W2 = (const float*)d_in[18];
  const float* b2 = (const float*)d_in[19];
  float* out = (float*)d_out;

  float* ws = (float*)d_ws;
  float* h_r   = ws;                 // 524288
  float* h_p   = h_r + 524288;       // 524288
  float* Mhat  = h_p + 524288;       // 1048576
  float* Msoft = Mhat + 1048576;     // 1048576
  float* rfr   = Msoft + 1048576;    // 262144
  float* rfp   = rfr + 262144;       // 262144
  float* u_r   = rfp + 262144;       // 524288
  float* u_p   = u_r + 524288;       // 524288
  float* agg_r = u_p + 524288;       // 524288
  float* agg_p = agg_r + 524288;     // 524288
  float* msg_r = agg_p + 524288;     // 4194304
  float* msg_p = msg_r + 4194304;    // 4194304
  int* ib      = (int*)(msg_p + 4194304);
  int* cnt_r  = ib;                  // 8192  (zeroed)
  int* cnt_p  = cnt_r + 8192;        // 8192  (zeroed)
  int* bar    = cnt_p + 8192;        // 1     (zeroed)
  int* off_r  = bar + 1;             // 8192
  int* off_p  = off_r + 8192;        // 8192
  int* rp_r   = off_p + 8192;        // 8193
  int* rp_p   = rp_r + 8193;         // 8193
  int* perm_r = rp_p + 8193;         // 65536
  int* perm_p = perm_r + 65536;      // 65536
  int* srcs_r = perm_p + 65536;      // 65536
  int* srcs_p = srcs_r + 65536;      // 65536

  // folded keys for the 3 iterations (host-side, deterministic)
  unsigned fk0[3], fk1[3];
  for (int it = 0; it < 3; ++it) {
    unsigned a = 0u, c = (unsigned)it;
    tf2x32(0u, 42u, a, c);
    fk0[it] = a; fk1[it] = c;
  }

  hipMemsetAsync(cnt_r, 0, (2 * 8192 + 1) * sizeof(int), stream);
  mega_kern<<<GRID, 256, 0, stream>>>(
      x_r, ei_r, ef_r, x_p, ei_p, ef_p,
      g1_Ws, g1_Wm, g1_We, g1_b, g2_Ws, g2_Wm, g2_We, g2_b,
      W1, b1, W2, b2, out,
      h_r, h_p, Mhat, Msoft, rfr, rfp, u_r, u_p, agg_r, agg_p, msg_r, msg_p,
      bar, cnt_r, cnt_p, off_r, off_p, rp_r, rp_p, perm_r, perm_p, srcs_r, srcs_p,
      fk0[0], fk1[0], fk0[1], fk1[1], fk0[2], fk1[2]);
}

// Round 8
// 710.993 us; speedup vs baseline: 3.7230x; 3.7230x over previous
//
#include <hip/hip_runtime.h>

// Problem constants
constexpr int kE = 65536, kNTOT = 8192;

// ---------------- threefry2x32 (JAX-exact, 20 rounds) ----------------
__host__ __device__ __forceinline__ void tf_round(unsigned& x0, unsigned& x1, int r) {
  x0 += x1;
  x1 = (x1 << r) | (x1 >> (32 - r));
  x1 ^= x0;
}
__host__ __device__ __forceinline__ void tf2x32(unsigned k0, unsigned k1,
                                                unsigned& x0, unsigned& x1) {
  unsigned ks2 = k0 ^ k1 ^ 0x1BD11BDAu;
  x0 += k0; x1 += k1;
  tf_round(x0,x1,13); tf_round(x0,x1,15); tf_round(x0,x1,26); tf_round(x0,x1,6);
  x0 += k1; x1 += ks2 + 1u;
  tf_round(x0,x1,17); tf_round(x0,x1,29); tf_round(x0,x1,16); tf_round(x0,x1,24);
  x0 += ks2; x1 += k0 + 2u;
  tf_round(x0,x1,13); tf_round(x0,x1,15); tf_round(x0,x1,26); tf_round(x0,x1,6);
  x0 += k0; x1 += k1 + 3u;
  tf_round(x0,x1,17); tf_round(x0,x1,29); tf_round(x0,x1,16); tf_round(x0,x1,24);
  x0 += k1; x1 += ks2 + 4u;
  tf_round(x0,x1,13); tf_round(x0,x1,15); tf_round(x0,x1,26); tf_round(x0,x1,6);
  x0 += ks2; x1 += k0 + 5u;
}

// bits -> N(0,1), replicating jax.random.normal f32 path (partitionable threefry)
__device__ __forceinline__ float bits_to_normal(unsigned bits) {
  float f = __uint_as_float((bits >> 9) | 0x3f800000u) - 1.0f;  // [0,1)
  const float LO = -0.99999994f;
  float u = fmaf(f, 2.0f, LO);
  u = fmaxf(u, LO);
  float w = -log1pf(-u * u);
  float p;
  if (w < 5.0f) {
    w -= 2.5f;
    p = 2.81022636e-08f;
    p = fmaf(p, w, 3.43273939e-07f);
    p = fmaf(p, w, -3.5233877e-06f);
    p = fmaf(p, w, -4.39150654e-06f);
    p = fmaf(p, w, 0.00021858087f);
    p = fmaf(p, w, -0.00125372503f);
    p = fmaf(p, w, -0.00417768164f);
    p = fmaf(p, w, 0.246640727f);
    p = fmaf(p, w, 1.50140941f);
  } else {
    w = sqrtf(w) - 3.0f;
    p = -0.000200214257f;
    p = fmaf(p, w, 0.000100950558f);
    p = fmaf(p, w, 0.00134934322f);
    p = fmaf(p, w, -0.00367342844f);
    p = fmaf(p, w, 0.00573950773f);
    p = fmaf(p, w, -0.0076224613f);
    p = fmaf(p, w, 0.00943887047f);
    p = fmaf(p, w, 1.00167406f);
    p = fmaf(p, w, 2.83297682f);
  }
  return 1.41421356f * (p * u);
}

__device__ __forceinline__ float redmax32(float v) {
#pragma unroll
  for (int o = 16; o > 0; o >>= 1) v = fmaxf(v, __shfl_xor(v, o));
  return v;
}
__device__ __forceinline__ float redsum32(float v) {
#pragma unroll
  for (int o = 16; o > 0; o >>= 1) v += __shfl_xor(v, o);
  return v;
}

// ========== CSR build, single block: hist + scan + scatter in LDS (both graphs) =====
__global__ __launch_bounds__(1024) void csr_build(
    const int* __restrict__ eiR, const int* __restrict__ eiP,
    int* __restrict__ rpR, int* __restrict__ permR, int* __restrict__ srcsR,
    int* __restrict__ rpP, int* __restrict__ permP, int* __restrict__ srcsP) {
  __shared__ int scnt[kNTOT];    // 32 KB: histogram, then running offsets
  __shared__ int wpart[16];
  int t = threadIdx.x;
  for (int g = 0; g < 2; ++g) {
    const int* ei = g ? eiP : eiR;
    int* rp = g ? rpP : rpR;
    int* perm = g ? permP : permR;
    int* srcs = g ? srcsP : srcsR;
#pragma unroll
    for (int i = 0; i < 8; ++i) scnt[t + i * 1024] = 0;
    __syncthreads();
#pragma unroll
    for (int i = 0; i < 64; ++i) {
      int e = t + i * 1024;
      atomicAdd(&scnt[ei[kE + e]], 1);
    }
    __syncthreads();
    // exclusive scan: thread owns scnt[t*8 .. t*8+8)
    int v[8]; int s = 0;
#pragma unroll
    for (int i = 0; i < 8; ++i) { v[i] = scnt[t * 8 + i]; s += v[i]; }
    int lane = t & 63, w = t >> 6;
    int incl = s;
#pragma unroll
    for (int o = 1; o < 64; o <<= 1) { int y = __shfl_up(incl, o); if (lane >= o) incl += y; }
    if (lane == 63) wpart[w] = incl;
    __syncthreads();
    int base = 0;
#pragma unroll
    for (int i = 0; i < 16; ++i) if (i < w) base += wpart[i];
    int running = base + incl - s;
#pragma unroll
    for (int i = 0; i < 8; ++i) {
      rp[t * 8 + i] = running;
      int nv = v[i];
      scnt[t * 8 + i] = running;    // becomes offset array
      running += nv;
    }
    if (t == 0) rp[kNTOT] = kE;
    __syncthreads();
#pragma unroll
    for (int i = 0; i < 64; ++i) {
      int e = t + i * 1024;
      int dst = ei[kE + e];
      int src = ei[e];
      int pos = atomicAdd(&scnt[dst], 1);
      perm[pos] = e;
      srcs[pos] = src;
    }
    __syncthreads();
  }
}

// ================= msg GEMM (both graphs): msg[i] = relu(x[srcs[i]]@Wm + ef[perm[i]]@We)
template <int KX>
__global__ __launch_bounds__(256) void msg_gemm(
    const float* __restrict__ xR, const float* __restrict__ efR,
    const int* __restrict__ srcsR, const int* __restrict__ permR,
    float* __restrict__ msgR,
    const float* __restrict__ xP, const float* __restrict__ efP,
    const int* __restrict__ srcsP, const int* __restrict__ permP,
    float* __restrict__ msgP,
    const float* __restrict__ Wm, const float* __restrict__ We) {
  constexpr int KT = KX + 16;
  __shared__ float sA[KT][68];   // transposed A-tile: [k][edge]
  __shared__ float sW[KT][68];   // [k][j]
  bool isP = blockIdx.x >= 1024;
  const float* x = isP ? xP : xR;
  const float* ef = isP ? efP : efR;
  const int* srcs = isP ? srcsP : srcsR;
  const int* perm = isP ? permP : permR;
  float* msg = isP ? msgP : msgR;
  int i0 = (blockIdx.x & 1023) * 64;
  int t = threadIdx.x;
#pragma unroll
  for (int idx = 0; idx < KT * 64 / 1024; ++idx) {
    int q = t * 4 + idx * 1024;
    int k = q >> 6, j = q & 63;
    const float* sp = (k < KX) ? (Wm + k * 64 + j) : (We + (k - KX) * 64 + j);
    float4 v = *reinterpret_cast<const float4*>(sp);
    *reinterpret_cast<float4*>(&sW[k][j]) = v;
  }
#pragma unroll
  for (int idx = 0; idx < KT * 64 / 1024; ++idx) {
    int q = t * 4 + idx * 1024;
    int r = q / KT;
    int k = q % KT;   // 4-aligned
    const float* rptr = (k < KX) ? (x + (size_t)srcs[i0 + r] * KX + k)
                                 : (ef + (size_t)perm[i0 + r] * 16 + (k - KX));
    float4 v = *reinterpret_cast<const float4*>(rptr);
    sA[k + 0][r] = v.x; sA[k + 1][r] = v.y; sA[k + 2][r] = v.z; sA[k + 3][r] = v.w;
  }
  __syncthreads();
  int tn = (t & 15) * 4;
  int tj = (t >> 4) * 4;
  float acc[4][4] = {};
#pragma unroll 8
  for (int k = 0; k < KT; ++k) {
    float4 a = *reinterpret_cast<const float4*>(&sA[k][tn]);
    float4 b = *reinterpret_cast<const float4*>(&sW[k][tj]);
    acc[0][0] = fmaf(a.x, b.x, acc[0][0]); acc[0][1] = fmaf(a.x, b.y, acc[0][1]);
    acc[0][2] = fmaf(a.x, b.z, acc[0][2]); acc[0][3] = fmaf(a.x, b.w, acc[0][3]);
    acc[1][0] = fmaf(a.y, b.x, acc[1][0]); acc[1][1] = fmaf(a.y, b.y, acc[1][1]);
    acc[1][2] = fmaf(a.y, b.z, acc[1][2]); acc[1][3] = fmaf(a.y, b.w, acc[1][3]);
    acc[2][0] = fmaf(a.z, b.x, acc[2][0]); acc[2][1] = fmaf(a.z, b.y, acc[2][1]);
    acc[2][2] = fmaf(a.z, b.z, acc[2][2]); acc[2][3] = fmaf(a.z, b.w, acc[2][3]);
    acc[3][0] = fmaf(a.w, b.x, acc[3][0]); acc[3][1] = fmaf(a.w, b.y, acc[3][1]);
    acc[3][2] = fmaf(a.w, b.z, acc[3][2]); acc[3][3] = fmaf(a.w, b.w, acc[3][3]);
  }
#pragma unroll
  for (int i = 0; i < 4; ++i) {
    float4 o;
    o.x = fmaxf(acc[i][0], 0.f); o.y = fmaxf(acc[i][1], 0.f);
    o.z = fmaxf(acc[i][2], 0.f); o.w = fmaxf(acc[i][3], 0.f);
    *reinterpret_cast<float4*>(&msg[(size_t)(i0 + tn + i) * 64 + tj]) = o;
  }
}

// ====== agg (dual-graph, 4096 blocks = 16384 waves for latency hiding) ======
__global__ __launch_bounds__(256) void agg_kern(
    const float* __restrict__ msgR, const int* __restrict__ rpR, float* __restrict__ aggR,
    const float* __restrict__ msgP, const int* __restrict__ rpP, float* __restrict__ aggP) {
  int lane = threadIdx.x & 63;
  int idx = blockIdx.x * 4 + (threadIdx.x >> 6);  // 0..16383
  const float* msg; const int* rp; float* agg;
  if (idx < kNTOT) { msg = msgR; rp = rpR; agg = aggR; }
  else { msg = msgP; rp = rpP; agg = aggP; idx -= kNTOT; }
  int s = rp[idx], e = rp[idx + 1];
  float acc = 0.f;
  for (int i = s; i < e; ++i) acc += msg[(size_t)i * 64 + lane];
  agg[(size_t)idx * 64 + lane] = acc;
}

// ====== node1 dense tiled GEMM: h = relu(X@Ws + agg + b), 64x64 tile/block ======
__global__ __launch_bounds__(256) void node1_gemm(
    const float* __restrict__ xR, const float* __restrict__ aggR, float* __restrict__ hR,
    const float* __restrict__ xP, const float* __restrict__ aggP, float* __restrict__ hP,
    const float* __restrict__ Ws, const float* __restrict__ bias) {
  __shared__ float sX[64][68];   // [k][row]
  __shared__ float sW[64][68];   // [k][col]
  bool isP = blockIdx.x >= 128;
  const float* x = isP ? xP : xR;
  const float* agg = isP ? aggP : aggR;
  float* h = isP ? hP : hR;
  int n0 = (blockIdx.x & 127) * 64;
  int t = threadIdx.x;
#pragma unroll
  for (int idx = 0; idx < 4; ++idx) {
    int q = t * 4 + idx * 1024;
    int k = q >> 6, j = q & 63;
    *reinterpret_cast<float4*>(&sW[k][j]) = *reinterpret_cast<const float4*>(Ws + q);
    float4 v = *reinterpret_cast<const float4*>(x + (size_t)n0 * 64 + q);
    sX[j + 0][k] = v.x; sX[j + 1][k] = v.y; sX[j + 2][k] = v.z; sX[j + 3][k] = v.w;
  }
  __syncthreads();
  int tn = (t & 15) * 4, tj = (t >> 4) * 4;
  float acc[4][4] = {};
#pragma unroll 8
  for (int k = 0; k < 64; ++k) {
    float4 a = *reinterpret_cast<const float4*>(&sX[k][tn]);
    float4 b = *reinterpret_cast<const float4*>(&sW[k][tj]);
    acc[0][0] = fmaf(a.x, b.x, acc[0][0]); acc[0][1] = fmaf(a.x, b.y, acc[0][1]);
    acc[0][2] = fmaf(a.x, b.z, acc[0][2]); acc[0][3] = fmaf(a.x, b.w, acc[0][3]);
    acc[1][0] = fmaf(a.y, b.x, acc[1][0]); acc[1][1] = fmaf(a.y, b.y, acc[1][1]);
    acc[1][2] = fmaf(a.y, b.z, acc[1][2]); acc[1][3] = fmaf(a.y, b.w, acc[1][3]);
    acc[2][0] = fmaf(a.z, b.x, acc[2][0]); acc[2][1] = fmaf(a.z, b.y, acc[2][1]);
    acc[2][2] = fmaf(a.z, b.z, acc[2][2]); acc[2][3] = fmaf(a.z, b.w, acc[2][3]);
    acc[3][0] = fmaf(a.w, b.x, acc[3][0]); acc[3][1] = fmaf(a.w, b.y, acc[3][1]);
    acc[3][2] = fmaf(a.w, b.z, acc[3][2]); acc[3][3] = fmaf(a.w, b.w, acc[3][3]);
  }
  float4 bv = *reinterpret_cast<const float4*>(bias + tj);
#pragma unroll
  for (int i = 0; i < 4; ++i) {
    int n = n0 + tn + i;
    float4 g = *reinterpret_cast<const float4*>(agg + (size_t)n * 64 + tj);
    float4 o;
    o.x = fmaxf(acc[i][0] + g.x + bv.x, 0.f);
    o.y = fmaxf(acc[i][1] + g.y + bv.y, 0.f);
    o.z = fmaxf(acc[i][2] + g.z + bv.z, 0.f);
    o.w = fmaxf(acc[i][3] + g.w + bv.w, 0.f);
    *reinterpret_cast<float4*>(&h[(size_t)n * 64 + tj]) = o;
  }
}

// ====== mhat_soft: Mhat tile + fused row softmax (->Msoft, ->out M0) + it0 RNG ======
// 512 blocks (batch x 8 r-chunks of 16), 256 threads.  [verified: R7 mega P7]
__global__ __launch_bounds__(256) void mhat_soft(
    const float* __restrict__ hR, const float* __restrict__ hP,
    float* __restrict__ Mhat, float* __restrict__ Msoft, float* __restrict__ M0out,
    float* __restrict__ rfr, unsigned fk0, unsigned fk1) {
  __shared__ float hr[16][66];
  __shared__ float hp[128][66];
  int gid = blockIdx.x, t = threadIdx.x;
  int gtid = (gid << 8) + t;
  // RNG for iteration 0 (all 262144 values across the 512-block grid, x2 per thread)
#pragma unroll
  for (int q = 0; q < 2; ++q) {
    unsigned i = (unsigned)gtid + (unsigned)q * 131072u;
    unsigned a0 = 0u, a1 = i;
    tf2x32(fk0, fk1, a0, a1);
    rfr[i] = bits_to_normal(a0 ^ a1);
  }
  int b = gid >> 3, r0 = (gid & 7) * 16;
  const float* hrG = hR + ((size_t)(b * 128 + r0)) * 64;
  {
    int q = t * 4; int r = q >> 6, d = q & 63;
    float4 v = *reinterpret_cast<const float4*>(hrG + q);
    hr[r][d] = v.x; hr[r][d + 1] = v.y; hr[r][d + 2] = v.z; hr[r][d + 3] = v.w;
  }
  const float* hpG = hP + (size_t)b * 128 * 64;
#pragma unroll
  for (int rep = 0; rep < 8; ++rep) {
    int q = (rep * 256 + t) * 4; int p = q >> 6, d = q & 63;
    float4 v = *reinterpret_cast<const float4*>(hpG + q);
    hp[p][d] = v.x; hp[p][d + 1] = v.y; hp[p][d + 2] = v.z; hp[p][d + 3] = v.w;
  }
  __syncthreads();
  int tx = t & 31, ty = t >> 5;
  float acc[2][4] = {};
  for (int d = 0; d < 64; ++d) {
    float a0 = hr[ty][d], a1 = hr[ty + 8][d];
    float q0 = hp[tx][d], q1 = hp[tx + 32][d], q2 = hp[tx + 64][d], q3 = hp[tx + 96][d];
    acc[0][0] = fmaf(a0, q0, acc[0][0]); acc[0][1] = fmaf(a0, q1, acc[0][1]);
    acc[0][2] = fmaf(a0, q2, acc[0][2]); acc[0][3] = fmaf(a0, q3, acc[0][3]);
    acc[1][0] = fmaf(a1, q0, acc[1][0]); acc[1][1] = fmaf(a1, q1, acc[1][1]);
    acc[1][2] = fmaf(a1, q2, acc[1][2]); acc[1][3] = fmaf(a1, q3, acc[1][3]);
  }
#pragma unroll
  for (int ii = 0; ii < 2; ++ii) {
    int r = r0 + ty + 8 * ii;
    float* mrow = Mhat + ((size_t)(b * 128 + r)) * 128;
    mrow[tx] = acc[ii][0]; mrow[tx + 32] = acc[ii][1];
    mrow[tx + 64] = acc[ii][2]; mrow[tx + 96] = acc[ii][3];
    float mx = redmax32(fmaxf(fmaxf(acc[ii][0], acc[ii][1]), fmaxf(acc[ii][2], acc[ii][3])));
    float e0 = __expf(acc[ii][0] - mx), e1 = __expf(acc[ii][1] - mx);
    float e2 = __expf(acc[ii][2] - mx), e3 = __expf(acc[ii][3] - mx);
    float inv = 1.0f / redsum32(e0 + e1 + e2 + e3);
    float* srow = Msoft + ((size_t)(b * 128 + r)) * 128;
    srow[tx] = e0 * inv; srow[tx + 32] = e1 * inv;
    srow[tx + 64] = e2 * inv; srow[tx + 96] = e3 * inv;
    float* orow = M0out + ((size_t)(b * 128 + r)) * 128;
    orow[tx] = e0 * inv; orow[tx + 32] = e1 * inv;
    orow[tx + 64] = e2 * inv; orow[tx + 96] = e3 * inv;
  }
}

// ====== rfp: rfp[b,p,i] = sum_r Msoft[b,r,p] * rfr[b,r,i]  (512 blocks) ======
// [verified: R7 mega phase A]
__global__ __launch_bounds__(256) void rfp_kern(
    const float* __restrict__ Msoft, const float* __restrict__ rfr,
    float* __restrict__ rfp) {
  __shared__ float rr[128][36];
  int b = blockIdx.x >> 3, p0 = (blockIdx.x & 7) * 16;
  int t = threadIdx.x;
  const float* rfG = rfr + (size_t)b * 4096;
#pragma unroll
  for (int rep = 0; rep < 4; ++rep) {
    int q = (rep * 256 + t) * 4; int r = q >> 5, i = q & 31;
    float4 v = *reinterpret_cast<const float4*>(rfG + q);
    rr[r][i] = v.x; rr[r][i + 1] = v.y; rr[r][i + 2] = v.z; rr[r][i + 3] = v.w;
  }
  __syncthreads();
  int pl = t & 15, ih = (t >> 4) * 2;
  int p = p0 + pl;
  const float* Mcol = Msoft + (size_t)b * 16384 + p;
  float a0 = 0.f, a1 = 0.f;
#pragma unroll 8
  for (int r = 0; r < 128; ++r) {
    float m = Mcol[(size_t)r * 128];
    a0 = fmaf(m, rr[r][ih], a0);
    a1 = fmaf(m, rr[r][ih + 1], a1);
  }
  float* dst = rfp + ((size_t)(b * 128 + p)) * 32 + ih;
  dst[0] = a0; dst[1] = a1;
}

// ====== node2u: o = relu(rf@Ws2 + agg + g2b); u = o@W1 (+b1 for r graph) ======
// 256 blocks. [verified: R7 mega phase D, incl. q>>6/&63 Ws2 staging]
__global__ __launch_bounds__(256) void node2u_gemm(
    const float* __restrict__ rfR, const float* __restrict__ aggR, float* __restrict__ uR,
    const float* __restrict__ rfP, const float* __restrict__ aggP, float* __restrict__ uP,
    const float* __restrict__ Ws2, const float* __restrict__ g2b,
    const float* __restrict__ W1, const float* __restrict__ b1) {
  __shared__ float sRF[32][68];
  __shared__ float sW2[32][68];
  __shared__ float sW1[64][68];
  __shared__ float sO[64][68];
  bool isP = blockIdx.x >= 128;
  const float* rf = isP ? rfP : rfR;
  const float* agg = isP ? aggP : aggR;
  float* u = isP ? uP : uR;
  int n0 = (blockIdx.x & 127) * 64;
  int t = threadIdx.x;
#pragma unroll
  for (int idx = 0; idx < 4; ++idx) {
    int q = t * 4 + idx * 1024;
    *reinterpret_cast<float4*>(&sW1[q >> 6][q & 63]) = *reinterpret_cast<const float4*>(W1 + q);
  }
#pragma unroll
  for (int idx = 0; idx < 2; ++idx) {
    int q = t * 4 + idx * 1024;
    // Ws2 is [32][64] row-major: row = q>>6, col = q&63
    *reinterpret_cast<float4*>(&sW2[q >> 6][q & 63]) = *reinterpret_cast<const float4*>(Ws2 + q);
    int r = q >> 5, kk = q & 31;
    float4 v = *reinterpret_cast<const float4*>(rf + (size_t)(n0 + r) * 32 + kk);
    sRF[kk][r] = v.x; sRF[kk + 1][r] = v.y; sRF[kk + 2][r] = v.z; sRF[kk + 3][r] = v.w;
  }
  __syncthreads();
  int tn = (t & 15) * 4, tj = (t >> 4) * 4;
  float acc[4][4] = {};
#pragma unroll 8
  for (int k = 0; k < 32; ++k) {
    float4 a = *reinterpret_cast<const float4*>(&sRF[k][tn]);
    float4 b = *reinterpret_cast<const float4*>(&sW2[k][tj]);
    acc[0][0] = fmaf(a.x, b.x, acc[0][0]); acc[0][1] = fmaf(a.x, b.y, acc[0][1]);
    acc[0][2] = fmaf(a.x, b.z, acc[0][2]); acc[0][3] = fmaf(a.x, b.w, acc[0][3]);
    acc[1][0] = fmaf(a.y, b.x, acc[1][0]); acc[1][1] = fmaf(a.y, b.y, acc[1][1]);
    acc[1][2] = fmaf(a.y, b.z, acc[1][2]); acc[1][3] = fmaf(a.y, b.w, acc[1][3]);
    acc[2][0] = fmaf(a.z, b.x, acc[2][0]); acc[2][1] = fmaf(a.z, b.y, acc[2][1]);
    acc[2][2] = fmaf(a.z, b.z, acc[2][2]); acc[2][3] = fmaf(a.z, b.w, acc[2][3]);
    acc[3][0] = fmaf(a.w, b.x, acc[3][0]); acc[3][1] = fmaf(a.w, b.y, acc[3][1]);
    acc[3][2] = fmaf(a.w, b.z, acc[3][2]); acc[3][3] = fmaf(a.w, b.w, acc[3][3]);
  }
  float4 bg = *reinterpret_cast<const float4*>(g2b + tj);
#pragma unroll
  for (int i = 0; i < 4; ++i) {
    int n = n0 + tn + i;
    float4 g = *reinterpret_cast<const float4*>(agg + (size_t)n * 64 + tj);
    sO[tj + 0][tn + i] = fmaxf(acc[i][0] + g.x + bg.x, 0.f);
    sO[tj + 1][tn + i] = fmaxf(acc[i][1] + g.y + bg.y, 0.f);
    sO[tj + 2][tn + i] = fmaxf(acc[i][2] + g.z + bg.z, 0.f);
    sO[tj + 3][tn + i] = fmaxf(acc[i][3] + g.w + bg.w, 0.f);
  }
  __syncthreads();
  float acc2[4][4] = {};
#pragma unroll 8
  for (int k = 0; k < 64; ++k) {
    float4 a = *reinterpret_cast<const float4*>(&sO[k][tn]);
    float4 b = *reinterpret_cast<const float4*>(&sW1[k][tj]);
    acc2[0][0] = fmaf(a.x, b.x, acc2[0][0]); acc2[0][1] = fmaf(a.x, b.y, acc2[0][1]);
    acc2[0][2] = fmaf(a.x, b.z, acc2[0][2]); acc2[0][3] = fmaf(a.x, b.w, acc2[0][3]);
    acc2[1][0] = fmaf(a.y, b.x, acc2[1][0]); acc2[1][1] = fmaf(a.y, b.y, acc2[1][1]);
    acc2[1][2] = fmaf(a.y, b.z, acc2[1][2]); acc2[1][3] = fmaf(a.y, b.w, acc2[1][3]);
    acc2[2][0] = fmaf(a.z, b.x, acc2[2][0]); acc2[2][1] = fmaf(a.z, b.y, acc2[2][1]);
    acc2[2][2] = fmaf(a.z, b.z, acc2[2][2]); acc2[2][3] = fmaf(a.z, b.w, acc2[2][3]);
    acc2[3][0] = fmaf(a.w, b.x, acc2[3][0]); acc2[3][1] = fmaf(a.w, b.y, acc2[3][1]);
    acc2[3][2] = fmaf(a.w, b.z, acc2[3][2]); acc2[3][3] = fmaf(a.w, b.w, acc2[3][3]);
  }
  float4 b1v = make_float4(0.f, 0.f, 0.f, 0.f);
  if (!isP) b1v = *reinterpret_cast<const float4*>(b1 + tj);
#pragma unroll
  for (int i = 0; i < 4; ++i) {
    int n = n0 + tn + i;
    float4 o;
    o.x = acc2[i][0] + b1v.x; o.y = acc2[i][1] + b1v.y;
    o.z = acc2[i][2] + b1v.z; o.w = acc2[i][3] + b1v.w;
    *reinterpret_cast<float4*>(&u[(size_t)n * 64 + tj]) = o;
  }
}

// ====== upd_soft: Mhat += pairwise MLP; fused row softmax -> (Msoft | final out);
//        optional RNG for next iteration. 512 blocks. [verified: R7 mega phase E] ======
__global__ __launch_bounds__(256) void upd_soft(
    const float* __restrict__ uR, const float* __restrict__ uP,
    const float* __restrict__ W2, const float* __restrict__ b2p,
    float* __restrict__ Mhat, float* __restrict__ softDst,
    int writeMhat, float* __restrict__ rfr, int doRng,
    unsigned fk0, unsigned fk1) {
  __shared__ float sur[16][66];
  __shared__ float sup[128][66];
  __shared__ float sw2[64];
  int gid = blockIdx.x, t = threadIdx.x;
  int b = gid >> 3, r0 = (gid & 7) * 16;
  const float* urG = uR + ((size_t)(b * 128 + r0)) * 64;
  {
    int q = t * 4; int r = q >> 6, d = q & 63;
    float4 v = *reinterpret_cast<const float4*>(urG + q);
    sur[r][d] = v.x; sur[r][d + 1] = v.y; sur[r][d + 2] = v.z; sur[r][d + 3] = v.w;
  }
  const float* upG = uP + (size_t)b * 128 * 64;
#pragma unroll
  for (int rep = 0; rep < 8; ++rep) {
    int q = (rep * 256 + t) * 4; int p = q >> 6, d = q & 63;
    float4 v = *reinterpret_cast<const float4*>(upG + q);
    sup[p][d] = v.x; sup[p][d + 1] = v.y; sup[p][d + 2] = v.z; sup[p][d + 3] = v.w;
  }
  if (t < 64) sw2[t] = W2[t];
  __syncthreads();
  int tx = t & 31, ty = t >> 5;
  float acc[2][4] = {};
  for (int j = 0; j < 64; ++j) {
    float w2v = sw2[j];
    float a0 = sur[ty][j], a1 = sur[ty + 8][j];
    float q0 = sup[tx][j], q1 = sup[tx + 32][j], q2 = sup[tx + 64][j], q3 = sup[tx + 96][j];
    acc[0][0] = fmaf(fmaxf(a0 - q0, 0.f), w2v, acc[0][0]);
    acc[0][1] = fmaf(fmaxf(a0 - q1, 0.f), w2v, acc[0][1]);
    acc[0][2] = fmaf(fmaxf(a0 - q2, 0.f), w2v, acc[0][2]);
    acc[0][3] = fmaf(fmaxf(a0 - q3, 0.f), w2v, acc[0][3]);
    acc[1][0] = fmaf(fmaxf(a1 - q0, 0.f), w2v, acc[1][0]);
    acc[1][1] = fmaf(fmaxf(a1 - q1, 0.f), w2v, acc[1][1]);
    acc[1][2] = fmaf(fmaxf(a1 - q2, 0.f), w2v, acc[1][2]);
    acc[1][3] = fmaf(fmaxf(a1 - q3, 0.f), w2v, acc[1][3]);
  }
  float b2v = b2p[0];
#pragma unroll
  for (int ii = 0; ii < 2; ++ii) {
    int r = r0 + ty + 8 * ii;
    float* mrow = Mhat + ((size_t)(b * 128 + r)) * 128;
    float m0 = mrow[tx] + acc[ii][0] + b2v;
    float m1 = mrow[tx + 32] + acc[ii][1] + b2v;
    float m2 = mrow[tx + 64] + acc[ii][2] + b2v;
    float m3 = mrow[tx + 96] + acc[ii][3] + b2v;
    if (writeMhat) {
      mrow[tx] = m0; mrow[tx + 32] = m1; mrow[tx + 64] = m2; mrow[tx + 96] = m3;
    }
    float mx = redmax32(fmaxf(fmaxf(m0, m1), fmaxf(m2, m3)));
    float e0 = __expf(m0 - mx), e1 = __expf(m1 - mx);
    float e2 = __expf(m2 - mx), e3 = __expf(m3 - mx);
    float inv = 1.0f / redsum32(e0 + e1 + e2 + e3);
    float* srow = softDst + ((size_t)(b * 128 + r)) * 128;
    srow[tx] = e0 * inv; srow[tx + 32] = e1 * inv;
    srow[tx + 64] = e2 * inv; srow[tx + 96] = e3 * inv;
  }
  if (doRng) {
    int gtid = (gid << 8) + t;
#pragma unroll
    for (int q = 0; q < 2; ++q) {
      unsigned i = (unsigned)gtid + (unsigned)q * 131072u;
      unsigned a0 = 0u, a1 = i;
      tf2x32(fk0, fk1, a0, a1);
      rfr[i] = bits_to_normal(a0 ^ a1);
    }
  }
}

extern "C" void kernel_launch(void* const* d_in, const int* in_sizes, int n_in,
                              void* d_out, int out_size, void* d_ws, size_t ws_size,
                              hipStream_t stream) {
  (void)in_sizes; (void)n_in; (void)out_size; (void)ws_size;
  const float* x_r  = (const float*)d_in[0];
  const int*   ei_r = (const int*)d_in[1];
  const float* ef_r = (const float*)d_in[2];
  const float* x_p  = (const float*)d_in[3];
  const int*   ei_p = (const int*)d_in[4];
  const float* ef_p = (const float*)d_in[5];
  const float* g1_Ws = (const float*)d_in[8];
  const float* g1_Wm = (const float*)d_in[9];
  const float* g1_We = (const float*)d_in[10];
  const float* g1_b  = (const float*)d_in[11];
  const float* g2_Ws = (const float*)d_in[12];
  const float* g2_Wm = (const float*)d_in[13];
  const float* g2_We = (const float*)d_in[14];
  const float* g2_b  = (const float*)d_in[15];
  const float* W1 = (const float*)d_in[16];
  const float* b1 = (const float*)d_in[17];
  const float* W2 = (const float*)d_in[18];
  const float* b2 = (const float*)d_in[19];
  float* out = (float*)d_out;

  float* ws = (float*)d_ws;
  float* h_r   = ws;                 // 524288
  float* h_p   = h_r + 524288;       // 524288
  float* Mhat  = h_p + 524288;       // 1048576
  float* Msoft = Mhat + 1048576;     // 1048576
  float* rfr   = Msoft + 1048576;    // 262144
  float* rfp   = rfr + 262144;       // 262144
  float* u_r   = rfp + 262144;       // 524288
  float* u_p   = u_r + 524288;       // 524288
  float* agg_r = u_p + 524288;       // 524288
  float* agg_p = agg_r + 524288;     // 524288
  float* msg_r = agg_p + 524288;     // 4194304
  float* msg_p = msg_r + 4194304;    // 4194304
  int* ib      = (int*)(msg_p + 4194304);
  int* rp_r   = ib;                  // 8193
  int* rp_p   = rp_r + 8193;         // 8193
  int* perm_r = rp_p + 8193;         // 65536
  int* perm_p = perm_r + 65536;      // 65536
  int* srcs_r = perm_p + 65536;      // 65536
  int* srcs_p = srcs_r + 65536;      // 65536

  // folded keys for the 3 iterations (host-side, deterministic)
  unsigned fk0[3], fk1[3];
  for (int it = 0; it < 3; ++it) {
    unsigned a = 0u, c = (unsigned)it;
    tf2x32(0u, 42u, a, c);
    fk0[it] = a; fk1[it] = c;
  }

  // ---- CSR build: one block, all in LDS (replaces memset+hist+scan+scatter) ----
  csr_build<<<1, 1024, 0, stream>>>(ei_r, ei_p, rp_r, perm_r, srcs_r,
                                    rp_p, perm_p, srcs_p);

  // ---- gnn1 ----
  msg_gemm<64><<<2048, 256, 0, stream>>>(x_r, ef_r, srcs_r, perm_r, msg_r,
                                         x_p, ef_p, srcs_p, perm_p, msg_p,
                                         g1_Wm, g1_We);
  agg_kern<<<4096, 256, 0, stream>>>(msg_r, rp_r, agg_r, msg_p, rp_p, agg_p);
  node1_gemm<<<256, 256, 0, stream>>>(x_r, agg_r, h_r, x_p, agg_p, h_p, g1_Ws, g1_b);
  mhat_soft<<<512, 256, 0, stream>>>(h_r, h_p, Mhat, Msoft, out, rfr, fk0[0], fk1[0]);

  for (int it = 0; it < 3; ++it) {
    rfp_kern<<<512, 256, 0, stream>>>(Msoft, rfr, rfp);
    msg_gemm<32><<<2048, 256, 0, stream>>>(rfr, ef_r, srcs_r, perm_r, msg_r,
                                           rfp, ef_p, srcs_p, perm_p, msg_p,
                                           g2_Wm, g2_We);
    agg_kern<<<4096, 256, 0, stream>>>(msg_r, rp_r, agg_r, msg_p, rp_p, agg_p);
    node2u_gemm<<<256, 256, 0, stream>>>(rfr, agg_r, u_r, rfp, agg_p, u_p,
                                         g2_Ws, g2_b, W1, b1);
    int last = (it == 2);
    upd_soft<<<512, 256, 0, stream>>>(u_r, u_p, W2, b2, Mhat,
                                      last ? (out + 1048576) : Msoft,
                                      /*writeMhat=*/!last,
                                      rfr, /*doRng=*/!last,
                                      fk0[it < 2 ? it + 1 : 0], fk1[it < 2 ? it + 1 : 0]);
  }
}

// Round 9
// 358.030 us; speedup vs baseline: 7.3932x; 1.9858x over previous
//
#include <hip/hip_runtime.h>

// Problem constants
constexpr int kE = 65536, kNTOT = 8192;

// ---------------- threefry2x32 (JAX-exact, 20 rounds) ----------------
__host__ __device__ __forceinline__ void tf_round(unsigned& x0, unsigned& x1, int r) {
  x0 += x1;
  x1 = (x1 << r) | (x1 >> (32 - r));
  x1 ^= x0;
}
__host__ __device__ __forceinline__ void tf2x32(unsigned k0, unsigned k1,
                                                unsigned& x0, unsigned& x1) {
  unsigned ks2 = k0 ^ k1 ^ 0x1BD11BDAu;
  x0 += k0; x1 += k1;
  tf_round(x0,x1,13); tf_round(x0,x1,15); tf_round(x0,x1,26); tf_round(x0,x1,6);
  x0 += k1; x1 += ks2 + 1u;
  tf_round(x0,x1,17); tf_round(x0,x1,29); tf_round(x0,x1,16); tf_round(x0,x1,24);
  x0 += ks2; x1 += k0 + 2u;
  tf_round(x0,x1,13); tf_round(x0,x1,15); tf_round(x0,x1,26); tf_round(x0,x1,6);
  x0 += k0; x1 += k1 + 3u;
  tf_round(x0,x1,17); tf_round(x0,x1,29); tf_round(x0,x1,16); tf_round(x0,x1,24);
  x0 += k1; x1 += ks2 + 4u;
  tf_round(x0,x1,13); tf_round(x0,x1,15); tf_round(x0,x1,26); tf_round(x0,x1,6);
  x0 += ks2; x1 += k0 + 5u;
}

// bits -> N(0,1), replicating jax.random.normal f32 path (partitionable threefry)
__device__ __forceinline__ float bits_to_normal(unsigned bits) {
  float f = __uint_as_float((bits >> 9) | 0x3f800000u) - 1.0f;  // [0,1)
  const float LO = -0.99999994f;
  float u = fmaf(f, 2.0f, LO);
  u = fmaxf(u, LO);
  float w = -log1pf(-u * u);
  float p;
  if (w < 5.0f) {
    w -= 2.5f;
    p = 2.81022636e-08f;
    p = fmaf(p, w, 3.43273939e-07f);
    p = fmaf(p, w, -3.5233877e-06f);
    p = fmaf(p, w, -4.39150654e-06f);
    p = fmaf(p, w, 0.00021858087f);
    p = fmaf(p, w, -0.00125372503f);
    p = fmaf(p, w, -0.00417768164f);
    p = fmaf(p, w, 0.246640727f);
    p = fmaf(p, w, 1.50140941f);
  } else {
    w = sqrtf(w) - 3.0f;
    p = -0.000200214257f;
    p = fmaf(p, w, 0.000100950558f);
    p = fmaf(p, w, 0.00134934322f);
    p = fmaf(p, w, -0.00367342844f);
    p = fmaf(p, w, 0.00573950773f);
    p = fmaf(p, w, -0.0076224613f);
    p = fmaf(p, w, 0.00943887047f);
    p = fmaf(p, w, 1.00167406f);
    p = fmaf(p, w, 2.83297682f);
  }
  return 1.41421356f * (p * u);
}

__device__ __forceinline__ float redmax32(float v) {
#pragma unroll
  for (int o = 16; o > 0; o >>= 1) v = fmaxf(v, __shfl_xor(v, o));
  return v;
}
__device__ __forceinline__ float redsum32(float v) {
#pragma unroll
  for (int o = 16; o > 0; o >>= 1) v += __shfl_xor(v, o);
  return v;
}

// ================= CSR build (multi-block, verified R5) =================
__global__ __launch_bounds__(256) void hist_kern(const int* __restrict__ eiR,
                                                 const int* __restrict__ eiP,
                                                 int* __restrict__ cntR,
                                                 int* __restrict__ cntP) {
  int i = blockIdx.x * 256 + threadIdx.x;  // 0..131071
  const int* ei = (i < kE) ? eiR : eiP;
  int* cnt = (i < kE) ? cntR : cntP;
  int e = i & (kE - 1);
  atomicAdd(&cnt[ei[kE + e]], 1);
}

// 2 blocks (one per graph), 256 threads: 32 elems/thread + hierarchical block scan
__global__ __launch_bounds__(256) void scan_kern(const int* __restrict__ cntR,
                                                 int* __restrict__ rpR, int* __restrict__ offR,
                                                 const int* __restrict__ cntP,
                                                 int* __restrict__ rpP, int* __restrict__ offP) {
  const int* cnt = blockIdx.x ? cntP : cntR;
  int* rp = blockIdx.x ? rpP : rpR;
  int* off = blockIdx.x ? offP : offR;
  int t = threadIdx.x;
  int base = t * 32;
  int v[32];
#pragma unroll
  for (int i = 0; i < 32; ++i) v[i] = cnt[base + i];
  int sum = 0;
#pragma unroll
  for (int i = 0; i < 32; ++i) sum += v[i];
  int lane = t & 63, w = t >> 6;
  int incl = sum;
#pragma unroll
  for (int o = 1; o < 64; o <<= 1) {
    int y = __shfl_up(incl, o);
    if (lane >= o) incl += y;
  }
  __shared__ int wsum[4];
  if (lane == 63) wsum[w] = incl;
  __syncthreads();
  int woff = 0;
#pragma unroll
  for (int i = 0; i < 4; ++i) if (i < w) woff += wsum[i];
  int running = woff + incl - sum;
#pragma unroll
  for (int i = 0; i < 32; ++i) {
    rp[base + i] = running;
    off[base + i] = running;
    running += v[i];
  }
  if (t == 0) rp[kNTOT] = kE;
}

__global__ __launch_bounds__(256) void scatter_kern(
    const int* __restrict__ eiR, const int* __restrict__ eiP,
    int* __restrict__ offR, int* __restrict__ offP,
    int* __restrict__ permR, int* __restrict__ permP,
    int* __restrict__ srcsR, int* __restrict__ srcsP) {
  int i = blockIdx.x * 256 + threadIdx.x;
  const int* ei = (i < kE) ? eiR : eiP;
  int* off = (i < kE) ? offR : offP;
  int* perm = (i < kE) ? permR : permP;
  int* srcs = (i < kE) ? srcsR : srcsP;
  int e = i & (kE - 1);
  int dst = ei[kE + e];
  int pos = atomicAdd(&off[dst], 1);
  perm[pos] = e;
  srcs[pos] = ei[e];
}

// ================= msg GEMM (both graphs): msg[i] = relu(x[srcs[i]]@Wm + ef[perm[i]]@We)
template <int KX>
__global__ __launch_bounds__(256) void msg_gemm(
    const float* __restrict__ xR, const float* __restrict__ efR,
    const int* __restrict__ srcsR, const int* __restrict__ permR,
    float* __restrict__ msgR,
    const float* __restrict__ xP, const float* __restrict__ efP,
    const int* __restrict__ srcsP, const int* __restrict__ permP,
    float* __restrict__ msgP,
    const float* __restrict__ Wm, const float* __restrict__ We) {
  constexpr int KT = KX + 16;
  __shared__ float sA[KT][68];   // transposed A-tile: [k][edge]
  __shared__ float sW[KT][68];   // [k][j]
  bool isP = blockIdx.x >= 1024;
  const float* x = isP ? xP : xR;
  const float* ef = isP ? efP : efR;
  const int* srcs = isP ? srcsP : srcsR;
  const int* perm = isP ? permP : permR;
  float* msg = isP ? msgP : msgR;
  int i0 = (blockIdx.x & 1023) * 64;
  int t = threadIdx.x;
#pragma unroll
  for (int idx = 0; idx < KT * 64 / 1024; ++idx) {
    int q = t * 4 + idx * 1024;
    int k = q >> 6, j = q & 63;
    const float* sp = (k < KX) ? (Wm + k * 64 + j) : (We + (k - KX) * 64 + j);
    float4 v = *reinterpret_cast<const float4*>(sp);
    *reinterpret_cast<float4*>(&sW[k][j]) = v;
  }
#pragma unroll
  for (int idx = 0; idx < KT * 64 / 1024; ++idx) {
    int q = t * 4 + idx * 1024;
    int r = q / KT;
    int k = q % KT;   // 4-aligned
    const float* rptr = (k < KX) ? (x + (size_t)srcs[i0 + r] * KX + k)
                                 : (ef + (size_t)perm[i0 + r] * 16 + (k - KX));
    float4 v = *reinterpret_cast<const float4*>(rptr);
    sA[k + 0][r] = v.x; sA[k + 1][r] = v.y; sA[k + 2][r] = v.z; sA[k + 3][r] = v.w;
  }
  __syncthreads();
  int tn = (t & 15) * 4;
  int tj = (t >> 4) * 4;
  float acc[4][4] = {};
#pragma unroll 8
  for (int k = 0; k < KT; ++k) {
    float4 a = *reinterpret_cast<const float4*>(&sA[k][tn]);
    float4 b = *reinterpret_cast<const float4*>(&sW[k][tj]);
    acc[0][0] = fmaf(a.x, b.x, acc[0][0]); acc[0][1] = fmaf(a.x, b.y, acc[0][1]);
    acc[0][2] = fmaf(a.x, b.z, acc[0][2]); acc[0][3] = fmaf(a.x, b.w, acc[0][3]);
    acc[1][0] = fmaf(a.y, b.x, acc[1][0]); acc[1][1] = fmaf(a.y, b.y, acc[1][1]);
    acc[1][2] = fmaf(a.y, b.z, acc[1][2]); acc[1][3] = fmaf(a.y, b.w, acc[1][3]);
    acc[2][0] = fmaf(a.z, b.x, acc[2][0]); acc[2][1] = fmaf(a.z, b.y, acc[2][1]);
    acc[2][2] = fmaf(a.z, b.z, acc[2][2]); acc[2][3] = fmaf(a.z, b.w, acc[2][3]);
    acc[3][0] = fmaf(a.w, b.x, acc[3][0]); acc[3][1] = fmaf(a.w, b.y, acc[3][1]);
    acc[3][2] = fmaf(a.w, b.z, acc[3][2]); acc[3][3] = fmaf(a.w, b.w, acc[3][3]);
  }
#pragma unroll
  for (int i = 0; i < 4; ++i) {
    float4 o;
    o.x = fmaxf(acc[i][0], 0.f); o.y = fmaxf(acc[i][1], 0.f);
    o.z = fmaxf(acc[i][2], 0.f); o.w = fmaxf(acc[i][3], 0.f);
    *reinterpret_cast<float4*>(&msg[(size_t)(i0 + tn + i) * 64 + tj]) = o;
  }
}

// ====== agg (dual-graph, 4096 blocks = 16384 waves for latency hiding) ======
__global__ __launch_bounds__(256) void agg_kern(
    const float* __restrict__ msgR, const int* __restrict__ rpR, float* __restrict__ aggR,
    const float* __restrict__ msgP, const int* __restrict__ rpP, float* __restrict__ aggP) {
  int lane = threadIdx.x & 63;
  int idx = blockIdx.x * 4 + (threadIdx.x >> 6);  // 0..16383
  const float* msg; const int* rp; float* agg;
  if (idx < kNTOT) { msg = msgR; rp = rpR; agg = aggR; }
  else { msg = msgP; rp = rpP; agg = aggP; idx -= kNTOT; }
  int s = rp[idx], e = rp[idx + 1];
  float acc = 0.f;
  for (int i = s; i < e; ++i) acc += msg[(size_t)i * 64 + lane];
  agg[(size_t)idx * 64 + lane] = acc;
}

// ====== node1 dense tiled GEMM: h = relu(X@Ws + agg + b), 64x64 tile/block ======
__global__ __launch_bounds__(256) void node1_gemm(
    const float* __restrict__ xR, const float* __restrict__ aggR, float* __restrict__ hR,
    const float* __restrict__ xP, const float* __restrict__ aggP, float* __restrict__ hP,
    const float* __restrict__ Ws, const float* __restrict__ bias) {
  __shared__ float sX[64][68];   // [k][row]
  __shared__ float sW[64][68];   // [k][col]
  bool isP = blockIdx.x >= 128;
  const float* x = isP ? xP : xR;
  const float* agg = isP ? aggP : aggR;
  float* h = isP ? hP : hR;
  int n0 = (blockIdx.x & 127) * 64;
  int t = threadIdx.x;
#pragma unroll
  for (int idx = 0; idx < 4; ++idx) {
    int q = t * 4 + idx * 1024;
    int k = q >> 6, j = q & 63;
    *reinterpret_cast<float4*>(&sW[k][j]) = *reinterpret_cast<const float4*>(Ws + q);
    float4 v = *reinterpret_cast<const float4*>(x + (size_t)n0 * 64 + q);
    sX[j + 0][k] = v.x; sX[j + 1][k] = v.y; sX[j + 2][k] = v.z; sX[j + 3][k] = v.w;
  }
  __syncthreads();
  int tn = (t & 15) * 4, tj = (t >> 4) * 4;
  float acc[4][4] = {};
#pragma unroll 8
  for (int k = 0; k < 64; ++k) {
    float4 a = *reinterpret_cast<const float4*>(&sX[k][tn]);
    float4 b = *reinterpret_cast<const float4*>(&sW[k][tj]);
    acc[0][0] = fmaf(a.x, b.x, acc[0][0]); acc[0][1] = fmaf(a.x, b.y, acc[0][1]);
    acc[0][2] = fmaf(a.x, b.z, acc[0][2]); acc[0][3] = fmaf(a.x, b.w, acc[0][3]);
    acc[1][0] = fmaf(a.y, b.x, acc[1][0]); acc[1][1] = fmaf(a.y, b.y, acc[1][1]);
    acc[1][2] = fmaf(a.y, b.z, acc[1][2]); acc[1][3] = fmaf(a.y, b.w, acc[1][3]);
    acc[2][0] = fmaf(a.z, b.x, acc[2][0]); acc[2][1] = fmaf(a.z, b.y, acc[2][1]);
    acc[2][2] = fmaf(a.z, b.z, acc[2][2]); acc[2][3] = fmaf(a.z, b.w, acc[2][3]);
    acc[3][0] = fmaf(a.w, b.x, acc[3][0]); acc[3][1] = fmaf(a.w, b.y, acc[3][1]);
    acc[3][2] = fmaf(a.w, b.z, acc[3][2]); acc[3][3] = fmaf(a.w, b.w, acc[3][3]);
  }
  float4 bv = *reinterpret_cast<const float4*>(bias + tj);
#pragma unroll
  for (int i = 0; i < 4; ++i) {
    int n = n0 + tn + i;
    float4 g = *reinterpret_cast<const float4*>(agg + (size_t)n * 64 + tj);
    float4 o;
    o.x = fmaxf(acc[i][0] + g.x + bv.x, 0.f);
    o.y = fmaxf(acc[i][1] + g.y + bv.y, 0.f);
    o.z = fmaxf(acc[i][2] + g.z + bv.z, 0.f);
    o.w = fmaxf(acc[i][3] + g.w + bv.w, 0.f);
    *reinterpret_cast<float4*>(&h[(size_t)n * 64 + tj]) = o;
  }
}

// ====== mhat_soft: Mhat tile + fused row softmax (->Msoft, ->out M0) + it0 RNG ======
__global__ __launch_bounds__(256) void mhat_soft(
    const float* __restrict__ hR, const float* __restrict__ hP,
    float* __restrict__ Mhat, float* __restrict__ Msoft, float* __restrict__ M0out,
    float* __restrict__ rfr, unsigned fk0, unsigned fk1) {
  __shared__ float hr[16][66];
  __shared__ float hp[128][66];
  int gid = blockIdx.x, t = threadIdx.x;
  int gtid = (gid << 8) + t;
#pragma unroll
  for (int q = 0; q < 2; ++q) {
    unsigned i = (unsigned)gtid + (unsigned)q * 131072u;
    unsigned a0 = 0u, a1 = i;
    tf2x32(fk0, fk1, a0, a1);
    rfr[i] = bits_to_normal(a0 ^ a1);
  }
  int b = gid >> 3, r0 = (gid & 7) * 16;
  const float* hrG = hR + ((size_t)(b * 128 + r0)) * 64;
  {
    int q = t * 4; int r = q >> 6, d = q & 63;
    float4 v = *reinterpret_cast<const float4*>(hrG + q);
    hr[r][d] = v.x; hr[r][d + 1] = v.y; hr[r][d + 2] = v.z; hr[r][d + 3] = v.w;
  }
  const float* hpG = hP + (size_t)b * 128 * 64;
#pragma unroll
  for (int rep = 0; rep < 8; ++rep) {
    int q = (rep * 256 + t) * 4; int p = q >> 6, d = q & 63;
    float4 v = *reinterpret_cast<const float4*>(hpG + q);
    hp[p][d] = v.x; hp[p][d + 1] = v.y; hp[p][d + 2] = v.z; hp[p][d + 3] = v.w;
  }
  __syncthreads();
  int tx = t & 31, ty = t >> 5;
  float acc[2][4] = {};
  for (int d = 0; d < 64; ++d) {
    float a0 = hr[ty][d], a1 = hr[ty + 8][d];
    float q0 = hp[tx][d], q1 = hp[tx + 32][d], q2 = hp[tx + 64][d], q3 = hp[tx + 96][d];
    acc[0][0] = fmaf(a0, q0, acc[0][0]); acc[0][1] = fmaf(a0, q1, acc[0][1]);
    acc[0][2] = fmaf(a0, q2, acc[0][2]); acc[0][3] = fmaf(a0, q3, acc[0][3]);
    acc[1][0] = fmaf(a1, q0, acc[1][0]); acc[1][1] = fmaf(a1, q1, acc[1][1]);
    acc[1][2] = fmaf(a1, q2, acc[1][2]); acc[1][3] = fmaf(a1, q3, acc[1][3]);
  }
#pragma unroll
  for (int ii = 0; ii < 2; ++ii) {
    int r = r0 + ty + 8 * ii;
    float* mrow = Mhat + ((size_t)(b * 128 + r)) * 128;
    mrow[tx] = acc[ii][0]; mrow[tx + 32] = acc[ii][1];
    mrow[tx + 64] = acc[ii][2]; mrow[tx + 96] = acc[ii][3];
    float mx = redmax32(fmaxf(fmaxf(acc[ii][0], acc[ii][1]), fmaxf(acc[ii][2], acc[ii][3])));
    float e0 = __expf(acc[ii][0] - mx), e1 = __expf(acc[ii][1] - mx);
    float e2 = __expf(acc[ii][2] - mx), e3 = __expf(acc[ii][3] - mx);
    float inv = 1.0f / redsum32(e0 + e1 + e2 + e3);
    float* srow = Msoft + ((size_t)(b * 128 + r)) * 128;
    srow[tx] = e0 * inv; srow[tx + 32] = e1 * inv;
    srow[tx + 64] = e2 * inv; srow[tx + 96] = e3 * inv;
    float* orow = M0out + ((size_t)(b * 128 + r)) * 128;
    orow[tx] = e0 * inv; orow[tx + 32] = e1 * inv;
    orow[tx + 64] = e2 * inv; orow[tx + 96] = e3 * inv;
  }
}

// ====== rfp: rfp[b,p,i] = sum_r Msoft[b,r,p] * rfr[b,r,i]  (512 blocks) ======
__global__ __launch_bounds__(256) void rfp_kern(
    const float* __restrict__ Msoft, const float* __restrict__ rfr,
    float* __restrict__ rfp) {
  __shared__ float rr[128][36];
  int b = blockIdx.x >> 3, p0 = (blockIdx.x & 7) * 16;
  int t = threadIdx.x;
  const float* rfG = rfr + (size_t)b * 4096;
#pragma unroll
  for (int rep = 0; rep < 4; ++rep) {
    int q = (rep * 256 + t) * 4; int r = q >> 5, i = q & 31;
    float4 v = *reinterpret_cast<const float4*>(rfG + q);
    rr[r][i] = v.x; rr[r][i + 1] = v.y; rr[r][i + 2] = v.z; rr[r][i + 3] = v.w;
  }
  __syncthreads();
  int pl = t & 15, ih = (t >> 4) * 2;
  int p = p0 + pl;
  const float* Mcol = Msoft + (size_t)b * 16384 + p;
  float a0 = 0.f, a1 = 0.f;
#pragma unroll 8
  for (int r = 0; r < 128; ++r) {
    float m = Mcol[(size_t)r * 128];
    a0 = fmaf(m, rr[r][ih], a0);
    a1 = fmaf(m, rr[r][ih + 1], a1);
  }
  float* dst = rfp + ((size_t)(b * 128 + p)) * 32 + ih;
  dst[0] = a0; dst[1] = a1;
}

// ====== node2u: o = relu(rf@Ws2 + agg + g2b); u = o@W1 (+b1 for r graph) ======
__global__ __launch_bounds__(256) void node2u_gemm(
    const float* __restrict__ rfR, const float* __restrict__ aggR, float* __restrict__ uR,
    const float* __restrict__ rfP, const float* __restrict__ aggP, float* __restrict__ uP,
    const float* __restrict__ Ws2, const float* __restrict__ g2b,
    const float* __restrict__ W1, const float* __restrict__ b1) {
  __shared__ float sRF[32][68];
  __shared__ float sW2[32][68];
  __shared__ float sW1[64][68];
  __shared__ float sO[64][68];
  bool isP = blockIdx.x >= 128;
  const float* rf = isP ? rfP : rfR;
  const float* agg = isP ? aggP : aggR;
  float* u = isP ? uP : uR;
  int n0 = (blockIdx.x & 127) * 64;
  int t = threadIdx.x;
#pragma unroll
  for (int idx = 0; idx < 4; ++idx) {
    int q = t * 4 + idx * 1024;
    *reinterpret_cast<float4*>(&sW1[q >> 6][q & 63]) = *reinterpret_cast<const float4*>(W1 + q);
  }
#pragma unroll
  for (int idx = 0; idx < 2; ++idx) {
    int q = t * 4 + idx * 1024;
    *reinterpret_cast<float4*>(&sW2[q >> 6][q & 63]) = *reinterpret_cast<const float4*>(Ws2 + q);
    int r = q >> 5, kk = q & 31;
    float4 v = *reinterpret_cast<const float4*>(rf + (size_t)(n0 + r) * 32 + kk);
    sRF[kk][r] = v.x; sRF[kk + 1][r] = v.y; sRF[kk + 2][r] = v.z; sRF[kk + 3][r] = v.w;
  }
  __syncthreads();
  int tn = (t & 15) * 4, tj = (t >> 4) * 4;
  float acc[4][4] = {};
#pragma unroll 8
  for (int k = 0; k < 32; ++k) {
    float4 a = *reinterpret_cast<const float4*>(&sRF[k][tn]);
    float4 b = *reinterpret_cast<const float4*>(&sW2[k][tj]);
    acc[0][0] = fmaf(a.x, b.x, acc[0][0]); acc[0][1] = fmaf(a.x, b.y, acc[0][1]);
    acc[0][2] = fmaf(a.x, b.z, acc[0][2]); acc[0][3] = fmaf(a.x, b.w, acc[0][3]);
    acc[1][0] = fmaf(a.y, b.x, acc[1][0]); acc[1][1] = fmaf(a.y, b.y, acc[1][1]);
    acc[1][2] = fmaf(a.y, b.z, acc[1][2]); acc[1][3] = fmaf(a.y, b.w, acc[1][3]);
    acc[2][0] = fmaf(a.z, b.x, acc[2][0]); acc[2][1] = fmaf(a.z, b.y, acc[2][1]);
    acc[2][2] = fmaf(a.z, b.z, acc[2][2]); acc[2][3] = fmaf(a.z, b.w, acc[2][3]);
    acc[3][0] = fmaf(a.w, b.x, acc[3][0]); acc[3][1] = fmaf(a.w, b.y, acc[3][1]);
    acc[3][2] = fmaf(a.w, b.z, acc[3][2]); acc[3][3] = fmaf(a.w, b.w, acc[3][3]);
  }
  float4 bg = *reinterpret_cast<const float4*>(g2b + tj);
#pragma unroll
  for (int i = 0; i < 4; ++i) {
    int n = n0 + tn + i;
    float4 g = *reinterpret_cast<const float4*>(agg + (size_t)n * 64 + tj);
    sO[tj + 0][tn + i] = fmaxf(acc[i][0] + g.x + bg.x, 0.f);
    sO[tj + 1][tn + i] = fmaxf(acc[i][1] + g.y + bg.y, 0.f);
    sO[tj + 2][tn + i] = fmaxf(acc[i][2] + g.z + bg.z, 0.f);
    sO[tj + 3][tn + i] = fmaxf(acc[i][3] + g.w + bg.w, 0.f);
  }
  __syncthreads();
  float acc2[4][4] = {};
#pragma unroll 8
  for (int k = 0; k < 64; ++k) {
    float4 a = *reinterpret_cast<const float4*>(&sO[k][tn]);
    float4 b = *reinterpret_cast<const float4*>(&sW1[k][tj]);
    acc2[0][0] = fmaf(a.x, b.x, acc2[0][0]); acc2[0][1] = fmaf(a.x, b.y, acc2[0][1]);
    acc2[0][2] = fmaf(a.x, b.z, acc2[0][2]); acc2[0][3] = fmaf(a.x, b.w, acc2[0][3]);
    acc2[1][0] = fmaf(a.y, b.x, acc2[1][0]); acc2[1][1] = fmaf(a.y, b.y, acc2[1][1]);
    acc2[1][2] = fmaf(a.y, b.z, acc2[1][2]); acc2[1][3] = fmaf(a.y, b.w, acc2[1][3]);
    acc2[2][0] = fmaf(a.z, b.x, acc2[2][0]); acc2[2][1] = fmaf(a.z, b.y, acc2[2][1]);
    acc2[2][2] = fmaf(a.z, b.z, acc2[2][2]); acc2[2][3] = fmaf(a.z, b.w, acc2[2][3]);
    acc2[3][0] = fmaf(a.w, b.x, acc2[3][0]); acc2[3][1] = fmaf(a.w, b.y, acc2[3][1]);
    acc2[3][2] = fmaf(a.w, b.z, acc2[3][2]); acc2[3][3] = fmaf(a.w, b.w, acc2[3][3]);
  }
  float4 b1v = make_float4(0.f, 0.f, 0.f, 0.f);
  if (!isP) b1v = *reinterpret_cast<const float4*>(b1 + tj);
#pragma unroll
  for (int i = 0; i < 4; ++i) {
    int n = n0 + tn + i;
    float4 o;
    o.x = acc2[i][0] + b1v.x; o.y = acc2[i][1] + b1v.y;
    o.z = acc2[i][2] + b1v.z; o.w = acc2[i][3] + b1v.w;
    *reinterpret_cast<float4*>(&u[(size_t)n * 64 + tj]) = o;
  }
}

// ====== upd_soft: Mhat += pairwise MLP; fused row softmax -> (Msoft | final out);
//        optional RNG for next iteration. 512 blocks. ======
__global__ __launch_bounds__(256) void upd_soft(
    const float* __restrict__ uR, const float* __restrict__ uP,
    const float* __restrict__ W2, const float* __restrict__ b2p,
    float* __restrict__ Mhat, float* __restrict__ softDst,
    int writeMhat, float* __restrict__ rfr, int doRng,
    unsigned fk0, unsigned fk1) {
  __shared__ float sur[16][66];
  __shared__ float sup[128][66];
  __shared__ float sw2[64];
  int gid = blockIdx.x, t = threadIdx.x;
  int b = gid >> 3, r0 = (gid & 7) * 16;
  const float* urG = uR + ((size_t)(b * 128 + r0)) * 64;
  {
    int q = t * 4; int r = q >> 6, d = q & 63;
    float4 v = *reinterpret_cast<const float4*>(urG + q);
    sur[r][d] = v.x; sur[r][d + 1] = v.y; sur[r][d + 2] = v.z; sur[r][d + 3] = v.w;
  }
  const float* upG = uP + (size_t)b * 128 * 64;
#pragma unroll
  for (int rep = 0; rep < 8; ++rep) {
    int q = (rep * 256 + t) * 4; int p = q >> 6, d = q & 63;
    float4 v = *reinterpret_cast<const float4*>(upG + q);
    sup[p][d] = v.x; sup[p][d + 1] = v.y; sup[p][d + 2] = v.z; sup[p][d + 3] = v.w;
  }
  if (t < 64) sw2[t] = W2[t];
  __syncthreads();
  int tx = t & 31, ty = t >> 5;
  float acc[2][4] = {};
  for (int j = 0; j < 64; ++j) {
    float w2v = sw2[j];
    float a0 = sur[ty][j], a1 = sur[ty + 8][j];
    float q0 = sup[tx][j], q1 = sup[tx + 32][j], q2 = sup[tx + 64][j], q3 = sup[tx + 96][j];
    acc[0][0] = fmaf(fmaxf(a0 - q0, 0.f), w2v, acc[0][0]);
    acc[0][1] = fmaf(fmaxf(a0 - q1, 0.f), w2v, acc[0][1]);
    acc[0][2] = fmaf(fmaxf(a0 - q2, 0.f), w2v, acc[0][2]);
    acc[0][3] = fmaf(fmaxf(a0 - q3, 0.f), w2v, acc[0][3]);
    acc[1][0] = fmaf(fmaxf(a1 - q0, 0.f), w2v, acc[1][0]);
    acc[1][1] = fmaf(fmaxf(a1 - q1, 0.f), w2v, acc[1][1]);
    acc[1][2] = fmaf(fmaxf(a1 - q2, 0.f), w2v, acc[1][2]);
    acc[1][3] = fmaf(fmaxf(a1 - q3, 0.f), w2v, acc[1][3]);
  }
  float b2v = b2p[0];
#pragma unroll
  for (int ii = 0; ii < 2; ++ii) {
    int r = r0 + ty + 8 * ii;
    float* mrow = Mhat + ((size_t)(b * 128 + r)) * 128;
    float m0 = mrow[tx] + acc[ii][0] + b2v;
    float m1 = mrow[tx + 32] + acc[ii][1] + b2v;
    float m2 = mrow[tx + 64] + acc[ii][2] + b2v;
    float m3 = mrow[tx + 96] + acc[ii][3] + b2v;
    if (writeMhat) {
      mrow[tx] = m0; mrow[tx + 32] = m1; mrow[tx + 64] = m2; mrow[tx + 96] = m3;
    }
    float mx = redmax32(fmaxf(fmaxf(m0, m1), fmaxf(m2, m3)));
    float e0 = __expf(m0 - mx), e1 = __expf(m1 - mx);
    float e2 = __expf(m2 - mx), e3 = __expf(m3 - mx);
    float inv = 1.0f / redsum32(e0 + e1 + e2 + e3);
    float* srow = softDst + ((size_t)(b * 128 + r)) * 128;
    srow[tx] = e0 * inv; srow[tx + 32] = e1 * inv;
    srow[tx + 64] = e2 * inv; srow[tx + 96] = e3 * inv;
  }
  if (doRng) {
    int gtid = (gid << 8) + t;
#pragma unroll
    for (int q = 0; q < 2; ++q) {
      unsigned i = (unsigned)gtid + (unsigned)q * 131072u;
      unsigned a0 = 0u, a1 = i;
      tf2x32(fk0, fk1, a0, a1);
      rfr[i] = bits_to_normal(a0 ^ a1);
    }
  }
}

extern "C" void kernel_launch(void* const* d_in, const int* in_sizes, int n_in,
                              void* d_out, int out_size, void* d_ws, size_t ws_size,
                              hipStream_t stream) {
  (void)in_sizes; (void)n_in; (void)out_size; (void)ws_size;
  const float* x_r  = (const float*)d_in[0];
  const int*   ei_r = (const int*)d_in[1];
  const float* ef_r = (const float*)d_in[2];
  const float* x_p  = (const float*)d_in[3];
  const int*   ei_p = (const int*)d_in[4];
  const float* ef_p = (const float*)d_in[5];
  const float* g1_Ws = (const float*)d_in[8];
  const float* g1_Wm = (const float*)d_in[9];
  const float* g1_We = (const float*)d_in[10];
  const float* g1_b  = (const float*)d_in[11];
  const float* g2_Ws = (const float*)d_in[12];
  const float* g2_Wm = (const float*)d_in[13];
  const float* g2_We = (const float*)d_in[14];
  const float* g2_b  = (const float*)d_in[15];
  const float* W1 = (const float*)d_in[16];
  const float* b1 = (const float*)d_in[17];
  const float* W2 = (const float*)d_in[18];
  const float* b2 = (const float*)d_in[19];
  float* out = (float*)d_out;

  float* ws = (float*)d_ws;
  float* h_r   = ws;                 // 524288
  float* h_p   = h_r + 524288;       // 524288
  float* Mhat  = h_p + 524288;       // 1048576
  float* Msoft = Mhat + 1048576;     // 1048576
  float* rfr   = Msoft + 1048576;    // 262144
  float* rfp   = rfr + 262144;       // 262144
  float* u_r   = rfp + 262144;       // 524288
  float* u_p   = u_r + 524288;       // 524288
  float* agg_r = u_p + 524288;       // 524288
  float* agg_p = agg_r + 524288;     // 524288
  float* msg_r = agg_p + 524288;     // 4194304
  float* msg_p = msg_r + 4194304;    // 4194304
  int* ib      = (int*)(msg_p + 4194304);
  int* cnt_r  = ib;                  // 8192 (zeroed)
  int* cnt_p  = cnt_r + 8192;        // 8192 (zeroed)
  int* off_r  = cnt_p + 8192;        // 8192
  int* off_p  = off_r + 8192;        // 8192
  int* rp_r   = off_p + 8192;        // 8193
  int* rp_p   = rp_r + 8193;         // 8193
  int* perm_r = rp_p + 8193;         // 65536
  int* perm_p = perm_r + 65536;      // 65536
  int* srcs_r = perm_p + 65536;      // 65536
  int* srcs_p = srcs_r + 65536;      // 65536

  // folded keys for the 3 iterations (host-side, deterministic)
  unsigned fk0[3], fk1[3];
  for (int it = 0; it < 3; ++it) {
    unsigned a = 0u, c = (unsigned)it;
    tf2x32(0u, 42u, a, c);
    fk0[it] = a; fk1[it] = c;
  }

  // ---- CSR build (multi-block; R8's single-block version was 500 µs — 1 CU latency-bound) ----
  hipMemsetAsync(cnt_r, 0, 2 * 8192 * sizeof(int), stream);
  hist_kern<<<512, 256, 0, stream>>>(ei_r, ei_p, cnt_r, cnt_p);
  scan_kern<<<2, 256, 0, stream>>>(cnt_r, rp_r, off_r, cnt_p, rp_p, off_p);
  scatter_kern<<<512, 256, 0, stream>>>(ei_r, ei_p, off_r, off_p,
                                        perm_r, perm_p, srcs_r, srcs_p);

  // ---- gnn1 ----
  msg_gemm<64><<<2048, 256, 0, stream>>>(x_r, ef_r, srcs_r, perm_r, msg_r,
                                         x_p, ef_p, srcs_p, perm_p, msg_p,
                                         g1_Wm, g1_We);
  agg_kern<<<4096, 256, 0, stream>>>(msg_r, rp_r, agg_r, msg_p, rp_p, agg_p);
  node1_gemm<<<256, 256, 0, stream>>>(x_r, agg_r, h_r, x_p, agg_p, h_p, g1_Ws, g1_b);
  mhat_soft<<<512, 256, 0, stream>>>(h_r, h_p, Mhat, Msoft, out, rfr, fk0[0], fk1[0]);

  for (int it = 0; it < 3; ++it) {
    rfp_kern<<<512, 256, 0, stream>>>(Msoft, rfr, rfp);
    msg_gemm<32><<<2048, 256, 0, stream>>>(rfr, ef_r, srcs_r, perm_r, msg_r,
                                           rfp, ef_p, srcs_p, perm_p, msg_p,
                                           g2_Wm, g2_We);
    agg_kern<<<4096, 256, 0, stream>>>(msg_r, rp_r, agg_r, msg_p, rp_p, agg_p);
    node2u_gemm<<<256, 256, 0, stream>>>(rfr, agg_r, u_r, rfp, agg_p, u_p,
                                         g2_Ws, g2_b, W1, b1);
    int last = (it == 2);
    upd_soft<<<512, 256, 0, stream>>>(u_r, u_p, W2, b2, Mhat,
                                      last ? (out + 1048576) : Msoft,
                                      /*writeMhat=*/!last,
                                      rfr, /*doRng=*/!last,
                                      fk0[it < 2 ? it + 1 : 0], fk1[it < 2 ? it + 1 : 0]);
  }
}

// Round 10
// 316.645 us; speedup vs baseline: 8.3595x; 1.1307x over previous
//
#include <hip/hip_runtime.h>

// Problem constants
constexpr int kE = 65536, kNTOT = 8192;

// ---------------- threefry2x32 (JAX-exact, 20 rounds) ----------------
__host__ __device__ __forceinline__ void tf_round(unsigned& x0, unsigned& x1, int r) {
  x0 += x1;
  x1 = (x1 << r) | (x1 >> (32 - r));
  x1 ^= x0;
}
__host__ __device__ __forceinline__ void tf2x32(unsigned k0, unsigned k1,
                                                unsigned& x0, unsigned& x1) {
  unsigned ks2 = k0 ^ k1 ^ 0x1BD11BDAu;
  x0 += k0; x1 += k1;
  tf_round(x0,x1,13); tf_round(x0,x1,15); tf_round(x0,x1,26); tf_round(x0,x1,6);
  x0 += k1; x1 += ks2 + 1u;
  tf_round(x0,x1,17); tf_round(x0,x1,29); tf_round(x0,x1,16); tf_round(x0,x1,24);
  x0 += ks2; x1 += k0 + 2u;
  tf_round(x0,x1,13); tf_round(x0,x1,15); tf_round(x0,x1,26); tf_round(x0,x1,6);
  x0 += k0; x1 += k1 + 3u;
  tf_round(x0,x1,17); tf_round(x0,x1,29); tf_round(x0,x1,16); tf_round(x0,x1,24);
  x0 += k1; x1 += ks2 + 4u;
  tf_round(x0,x1,13); tf_round(x0,x1,15); tf_round(x0,x1,26); tf_round(x0,x1,6);
  x0 += ks2; x1 += k0 + 5u;
}

// bits -> N(0,1), replicating jax.random.normal f32 path (partitionable threefry)
__device__ __forceinline__ float bits_to_normal(unsigned bits) {
  float f = __uint_as_float((bits >> 9) | 0x3f800000u) - 1.0f;  // [0,1)
  const float LO = -0.99999994f;
  float u = fmaf(f, 2.0f, LO);
  u = fmaxf(u, LO);
  float w = -log1pf(-u * u);
  float p;
  if (w < 5.0f) {
    w -= 2.5f;
    p = 2.81022636e-08f;
    p = fmaf(p, w, 3.43273939e-07f);
    p = fmaf(p, w, -3.5233877e-06f);
    p = fmaf(p, w, -4.39150654e-06f);
    p = fmaf(p, w, 0.00021858087f);
    p = fmaf(p, w, -0.00125372503f);
    p = fmaf(p, w, -0.00417768164f);
    p = fmaf(p, w, 0.246640727f);
    p = fmaf(p, w, 1.50140941f);
  } else {
    w = sqrtf(w) - 3.0f;
    p = -0.000200214257f;
    p = fmaf(p, w, 0.000100950558f);
    p = fmaf(p, w, 0.00134934322f);
    p = fmaf(p, w, -0.00367342844f);
    p = fmaf(p, w, 0.00573950773f);
    p = fmaf(p, w, -0.0076224613f);
    p = fmaf(p, w, 0.00943887047f);
    p = fmaf(p, w, 1.00167406f);
    p = fmaf(p, w, 2.83297682f);
  }
  return 1.41421356f * (p * u);
}

__device__ __forceinline__ float redmax32(float v) {
#pragma unroll
  for (int o = 16; o > 0; o >>= 1) v = fmaxf(v, __shfl_xor(v, o));
  return v;
}
__device__ __forceinline__ float redsum32(float v) {
#pragma unroll
  for (int o = 16; o > 0; o >>= 1) v += __shfl_xor(v, o);
  return v;
}

// ================= CSR build (multi-block) + agg zeroing =================
__global__ __launch_bounds__(256) void hist_kern(const int* __restrict__ eiR,
                                                 const int* __restrict__ eiP,
                                                 int* __restrict__ cntR,
                                                 int* __restrict__ cntP,
                                                 float* __restrict__ aggz) {
  int i = blockIdx.x * 256 + threadIdx.x;  // 0..131071
  // zero agg_r+agg_p (contiguous 1048576 floats) for the atomic accumulation
  float4 z4 = make_float4(0.f, 0.f, 0.f, 0.f);
  float4* z = reinterpret_cast<float4*>(aggz) + i * 2;
  z[0] = z4; z[1] = z4;
  const int* ei = (i < kE) ? eiR : eiP;
  int* cnt = (i < kE) ? cntR : cntP;
  int e = i & (kE - 1);
  atomicAdd(&cnt[ei[kE + e]], 1);
}

// 2 blocks (one per graph), 256 threads: 32 elems/thread + hierarchical block scan
__global__ __launch_bounds__(256) void scan_kern(const int* __restrict__ cntR,
                                                 int* __restrict__ rpR, int* __restrict__ offR,
                                                 const int* __restrict__ cntP,
                                                 int* __restrict__ rpP, int* __restrict__ offP) {
  const int* cnt = blockIdx.x ? cntP : cntR;
  int* rp = blockIdx.x ? rpP : rpR;
  int* off = blockIdx.x ? offP : offR;
  int t = threadIdx.x;
  int base = t * 32;
  int v[32];
#pragma unroll
  for (int i = 0; i < 32; ++i) v[i] = cnt[base + i];
  int sum = 0;
#pragma unroll
  for (int i = 0; i < 32; ++i) sum += v[i];
  int lane = t & 63, w = t >> 6;
  int incl = sum;
#pragma unroll
  for (int o = 1; o < 64; o <<= 1) {
    int y = __shfl_up(incl, o);
    if (lane >= o) incl += y;
  }
  __shared__ int wsum[4];
  if (lane == 63) wsum[w] = incl;
  __syncthreads();
  int woff = 0;
#pragma unroll
  for (int i = 0; i < 4; ++i) if (i < w) woff += wsum[i];
  int running = woff + incl - sum;
#pragma unroll
  for (int i = 0; i < 32; ++i) {
    rp[base + i] = running;
    off[base + i] = running;
    running += v[i];
  }
  if (t == 0) rp[kNTOT] = kE;
}

__global__ __launch_bounds__(256) void scatter_kern(
    const int* __restrict__ eiR, const int* __restrict__ eiP,
    int* __restrict__ offR, int* __restrict__ offP,
    int* __restrict__ permR, int* __restrict__ permP,
    int* __restrict__ srcsR, int* __restrict__ srcsP,
    int* __restrict__ dstsR, int* __restrict__ dstsP) {
  int i = blockIdx.x * 256 + threadIdx.x;
  const int* ei = (i < kE) ? eiR : eiP;
  int* off = (i < kE) ? offR : offP;
  int* perm = (i < kE) ? permR : permP;
  int* srcs = (i < kE) ? srcsR : srcsP;
  int* dsts = (i < kE) ? dstsR : dstsP;
  int e = i & (kE - 1);
  int dst = ei[kE + e];
  int pos = atomicAdd(&off[dst], 1);
  perm[pos] = e;
  srcs[pos] = ei[e];
  dsts[pos] = dst;
}

// ====== msg GEMM + fused segment-reduce aggregation (both graphs) ======
// Computes relu(x[srcs[i]]@Wm + ef[perm[i]]@We) for a 64-edge tile, then
// segment-reduces over equal-dst runs (CSR-sorted) and atomically adds to agg.
template <int KX>
__global__ __launch_bounds__(256) void msg_gemm(
    const float* __restrict__ xR, const float* __restrict__ efR,
    const int* __restrict__ srcsR, const int* __restrict__ permR,
    const int* __restrict__ dstsR, float* __restrict__ aggR,
    const float* __restrict__ xP, const float* __restrict__ efP,
    const int* __restrict__ srcsP, const int* __restrict__ permP,
    const int* __restrict__ dstsP, float* __restrict__ aggP,
    const float* __restrict__ Wm, const float* __restrict__ We) {
  constexpr int KT = KX + 16;
  constexpr int SA_ROWS = (KT > 64) ? KT : 64;   // sA reused as 64x68 output tile
  __shared__ float sA[SA_ROWS][68];
  __shared__ float sW[KT][68];
  __shared__ int sDst[64];
  bool isP = blockIdx.x >= 1024;
  const float* x = isP ? xP : xR;
  const float* ef = isP ? efP : efR;
  const int* srcs = isP ? srcsP : srcsR;
  const int* perm = isP ? permP : permR;
  const int* dsts = isP ? dstsP : dstsR;
  float* agg = isP ? aggP : aggR;
  int i0 = (blockIdx.x & 1023) * 64;
  int t = threadIdx.x;
#pragma unroll
  for (int idx = 0; idx < KT * 64 / 1024; ++idx) {
    int q = t * 4 + idx * 1024;
    int k = q >> 6, j = q & 63;
    const float* sp = (k < KX) ? (Wm + k * 64 + j) : (We + (k - KX) * 64 + j);
    float4 v = *reinterpret_cast<const float4*>(sp);
    *reinterpret_cast<float4*>(&sW[k][j]) = v;
  }
  if (t < 64) sDst[t] = dsts[i0 + t];
#pragma unroll
  for (int idx = 0; idx < KT * 64 / 1024; ++idx) {
    int q = t * 4 + idx * 1024;
    int r = q / KT;
    int k = q % KT;   // 4-aligned
    const float* rptr = (k < KX) ? (x + (size_t)srcs[i0 + r] * KX + k)
                                 : (ef + (size_t)perm[i0 + r] * 16 + (k - KX));
    float4 v = *reinterpret_cast<const float4*>(rptr);
    sA[k + 0][r] = v.x; sA[k + 1][r] = v.y; sA[k + 2][r] = v.z; sA[k + 3][r] = v.w;
  }
  __syncthreads();
  int tn = (t & 15) * 4;
  int tj = (t >> 4) * 4;
  float acc[4][4] = {};
#pragma unroll 8
  for (int k = 0; k < KT; ++k) {
    float4 a = *reinterpret_cast<const float4*>(&sA[k][tn]);
    float4 b = *reinterpret_cast<const float4*>(&sW[k][tj]);
    acc[0][0] = fmaf(a.x, b.x, acc[0][0]); acc[0][1] = fmaf(a.x, b.y, acc[0][1]);
    acc[0][2] = fmaf(a.x, b.z, acc[0][2]); acc[0][3] = fmaf(a.x, b.w, acc[0][3]);
    acc[1][0] = fmaf(a.y, b.x, acc[1][0]); acc[1][1] = fmaf(a.y, b.y, acc[1][1]);
    acc[1][2] = fmaf(a.y, b.z, acc[1][2]); acc[1][3] = fmaf(a.y, b.w, acc[1][3]);
    acc[2][0] = fmaf(a.z, b.x, acc[2][0]); acc[2][1] = fmaf(a.z, b.y, acc[2][1]);
    acc[2][2] = fmaf(a.z, b.z, acc[2][2]); acc[2][3] = fmaf(a.z, b.w, acc[2][3]);
    acc[3][0] = fmaf(a.w, b.x, acc[3][0]); acc[3][1] = fmaf(a.w, b.y, acc[3][1]);
    acc[3][2] = fmaf(a.w, b.z, acc[3][2]); acc[3][3] = fmaf(a.w, b.w, acc[3][3]);
  }
  __syncthreads();            // all sA reads done; reuse sA as output tile sO[row][col]
#pragma unroll
  for (int i = 0; i < 4; ++i) {
    sA[tn + i][tj + 0] = fmaxf(acc[i][0], 0.f);
    sA[tn + i][tj + 1] = fmaxf(acc[i][1], 0.f);
    sA[tn + i][tj + 2] = fmaxf(acc[i][2], 0.f);
    sA[tn + i][tj + 3] = fmaxf(acc[i][3], 0.f);
  }
  __syncthreads();
  // segment-reduce: 64 cols x 4 row-chunks of 16; one atomic per dst-run per col
  int col = t & 63;
  int r0l = (t >> 6) * 16;
  float run = 0.f;
  int rd = sDst[r0l];
#pragma unroll
  for (int r = 0; r < 16; ++r) {
    int d = sDst[r0l + r];
    if (d != rd) {
      unsafeAtomicAdd(&agg[(size_t)rd * 64 + col], run);
      run = 0.f; rd = d;
    }
    run += sA[r0l + r][col];
  }
  unsafeAtomicAdd(&agg[(size_t)rd * 64 + col], run);
}

// ====== node1 dense tiled GEMM: h = relu(X@Ws + agg + b); re-zeroes agg ======
__global__ __launch_bounds__(256) void node1_gemm(
    const float* __restrict__ xR, float* __restrict__ aggR, float* __restrict__ hR,
    const float* __restrict__ xP, float* __restrict__ aggP, float* __restrict__ hP,
    const float* __restrict__ Ws, const float* __restrict__ bias) {
  __shared__ float sX[64][68];   // [k][row]
  __shared__ float sW[64][68];   // [k][col]
  bool isP = blockIdx.x >= 128;
  const float* x = isP ? xP : xR;
  float* agg = isP ? aggP : aggR;
  float* h = isP ? hP : hR;
  int n0 = (blockIdx.x & 127) * 64;
  int t = threadIdx.x;
#pragma unroll
  for (int idx = 0; idx < 4; ++idx) {
    int q = t * 4 + idx * 1024;
    int k = q >> 6, j = q & 63;
    *reinterpret_cast<float4*>(&sW[k][j]) = *reinterpret_cast<const float4*>(Ws + q);
    float4 v = *reinterpret_cast<const float4*>(x + (size_t)n0 * 64 + q);
    sX[j + 0][k] = v.x; sX[j + 1][k] = v.y; sX[j + 2][k] = v.z; sX[j + 3][k] = v.w;
  }
  __syncthreads();
  int tn = (t & 15) * 4, tj = (t >> 4) * 4;
  float acc[4][4] = {};
#pragma unroll 8
  for (int k = 0; k < 64; ++k) {
    float4 a = *reinterpret_cast<const float4*>(&sX[k][tn]);
    float4 b = *reinterpret_cast<const float4*>(&sW[k][tj]);
    acc[0][0] = fmaf(a.x, b.x, acc[0][0]); acc[0][1] = fmaf(a.x, b.y, acc[0][1]);
    acc[0][2] = fmaf(a.x, b.z, acc[0][2]); acc[0][3] = fmaf(a.x, b.w, acc[0][3]);
    acc[1][0] = fmaf(a.y, b.x, acc[1][0]); acc[1][1] = fmaf(a.y, b.y, acc[1][1]);
    acc[1][2] = fmaf(a.y, b.z, acc[1][2]); acc[1][3] = fmaf(a.y, b.w, acc[1][3]);
    acc[2][0] = fmaf(a.z, b.x, acc[2][0]); acc[2][1] = fmaf(a.z, b.y, acc[2][1]);
    acc[2][2] = fmaf(a.z, b.z, acc[2][2]); acc[2][3] = fmaf(a.z, b.w, acc[2][3]);
    acc[3][0] = fmaf(a.w, b.x, acc[3][0]); acc[3][1] = fmaf(a.w, b.y, acc[3][1]);
    acc[3][2] = fmaf(a.w, b.z, acc[3][2]); acc[3][3] = fmaf(a.w, b.w, acc[3][3]);
  }
  float4 bv = *reinterpret_cast<const float4*>(bias + tj);
  float4 z4 = make_float4(0.f, 0.f, 0.f, 0.f);
#pragma unroll
  for (int i = 0; i < 4; ++i) {
    int n = n0 + tn + i;
    float4 g = *reinterpret_cast<const float4*>(&agg[(size_t)n * 64 + tj]);
    *reinterpret_cast<float4*>(&agg[(size_t)n * 64 + tj]) = z4;  // re-arm for next iter
    float4 o;
    o.x = fmaxf(acc[i][0] + g.x + bv.x, 0.f);
    o.y = fmaxf(acc[i][1] + g.y + bv.y, 0.f);
    o.z = fmaxf(acc[i][2] + g.z + bv.z, 0.f);
    o.w = fmaxf(acc[i][3] + g.w + bv.w, 0.f);
    *reinterpret_cast<float4*>(&h[(size_t)n * 64 + tj]) = o;
  }
}

// ====== mhat_soft: Mhat tile + fused row softmax (->Msoft, ->out M0) + it0 RNG ======
__global__ __launch_bounds__(256) void mhat_soft(
    const float* __restrict__ hR, const float* __restrict__ hP,
    float* __restrict__ Mhat, float* __restrict__ Msoft, float* __restrict__ M0out,
    float* __restrict__ rfr, unsigned fk0, unsigned fk1) {
  __shared__ float hr[16][66];
  __shared__ float hp[128][66];
  int gid = blockIdx.x, t = threadIdx.x;
  int gtid = (gid << 8) + t;
#pragma unroll
  for (int q = 0; q < 2; ++q) {
    unsigned i = (unsigned)gtid + (unsigned)q * 131072u;
    unsigned a0 = 0u, a1 = i;
    tf2x32(fk0, fk1, a0, a1);
    rfr[i] = bits_to_normal(a0 ^ a1);
  }
  int b = gid >> 3, r0 = (gid & 7) * 16;
  const float* hrG = hR + ((size_t)(b * 128 + r0)) * 64;
  {
    int q = t * 4; int r = q >> 6, d = q & 63;
    float4 v = *reinterpret_cast<const float4*>(hrG + q);
    hr[r][d] = v.x; hr[r][d + 1] = v.y; hr[r][d + 2] = v.z; hr[r][d + 3] = v.w;
  }
  const float* hpG = hP + (size_t)b * 128 * 64;
#pragma unroll
  for (int rep = 0; rep < 8; ++rep) {
    int q = (rep * 256 + t) * 4; int p = q >> 6, d = q & 63;
    float4 v = *reinterpret_cast<const float4*>(hpG + q);
    hp[p][d] = v.x; hp[p][d + 1] = v.y; hp[p][d + 2] = v.z; hp[p][d + 3] = v.w;
  }
  __syncthreads();
  int tx = t & 31, ty = t >> 5;
  float acc[2][4] = {};
  for (int d = 0; d < 64; ++d) {
    float a0 = hr[ty][d], a1 = hr[ty + 8][d];
    float q0 = hp[tx][d], q1 = hp[tx + 32][d], q2 = hp[tx + 64][d], q3 = hp[tx + 96][d];
    acc[0][0] = fmaf(a0, q0, acc[0][0]); acc[0][1] = fmaf(a0, q1, acc[0][1]);
    acc[0][2] = fmaf(a0, q2, acc[0][2]); acc[0][3] = fmaf(a0, q3, acc[0][3]);
    acc[1][0] = fmaf(a1, q0, acc[1][0]); acc[1][1] = fmaf(a1, q1, acc[1][1]);
    acc[1][2] = fmaf(a1, q2, acc[1][2]); acc[1][3] = fmaf(a1, q3, acc[1][3]);
  }
#pragma unroll
  for (int ii = 0; ii < 2; ++ii) {
    int r = r0 + ty + 8 * ii;
    float* mrow = Mhat + ((size_t)(b * 128 + r)) * 128;
    mrow[tx] = acc[ii][0]; mrow[tx + 32] = acc[ii][1];
    mrow[tx + 64] = acc[ii][2]; mrow[tx + 96] = acc[ii][3];
    float mx = redmax32(fmaxf(fmaxf(acc[ii][0], acc[ii][1]), fmaxf(acc[ii][2], acc[ii][3])));
    float e0 = __expf(acc[ii][0] - mx), e1 = __expf(acc[ii][1] - mx);
    float e2 = __expf(acc[ii][2] - mx), e3 = __expf(acc[ii][3] - mx);
    float inv = 1.0f / redsum32(e0 + e1 + e2 + e3);
    float* srow = Msoft + ((size_t)(b * 128 + r)) * 128;
    srow[tx] = e0 * inv; srow[tx + 32] = e1 * inv;
    srow[tx + 64] = e2 * inv; srow[tx + 96] = e3 * inv;
    float* orow = M0out + ((size_t)(b * 128 + r)) * 128;
    orow[tx] = e0 * inv; orow[tx + 32] = e1 * inv;
    orow[tx + 64] = e2 * inv; orow[tx + 96] = e3 * inv;
  }
}

// ====== rfp: rfp[b,p,i] = sum_r Msoft[b,r,p] * rfr[b,r,i]  (512 blocks) ======
__global__ __launch_bounds__(256) void rfp_kern(
    const float* __restrict__ Msoft, const float* __restrict__ rfr,
    float* __restrict__ rfp) {
  __shared__ float rr[128][36];
  int b = blockIdx.x >> 3, p0 = (blockIdx.x & 7) * 16;
  int t = threadIdx.x;
  const float* rfG = rfr + (size_t)b * 4096;
#pragma unroll
  for (int rep = 0; rep < 4; ++rep) {
    int q = (rep * 256 + t) * 4; int r = q >> 5, i = q & 31;
    float4 v = *reinterpret_cast<const float4*>(rfG + q);
    rr[r][i] = v.x; rr[r][i + 1] = v.y; rr[r][i + 2] = v.z; rr[r][i + 3] = v.w;
  }
  __syncthreads();
  int pl = t & 15, ih = (t >> 4) * 2;
  int p = p0 + pl;
  const float* Mcol = Msoft + (size_t)b * 16384 + p;
  float a0 = 0.f, a1 = 0.f;
#pragma unroll 8
  for (int r = 0; r < 128; ++r) {
    float m = Mcol[(size_t)r * 128];
    a0 = fmaf(m, rr[r][ih], a0);
    a1 = fmaf(m, rr[r][ih + 1], a1);
  }
  float* dst = rfp + ((size_t)(b * 128 + p)) * 32 + ih;
  dst[0] = a0; dst[1] = a1;
}

// ====== node2u: o = relu(rf@Ws2 + agg + g2b); u = o@W1 (+b1 for r graph);
//        re-zeroes agg after reading ======
__global__ __launch_bounds__(256) void node2u_gemm(
    const float* __restrict__ rfR, float* __restrict__ aggR, float* __restrict__ uR,
    const float* __restrict__ rfP, float* __restrict__ aggP, float* __restrict__ uP,
    const float* __restrict__ Ws2, const float* __restrict__ g2b,
    const float* __restrict__ W1, const float* __restrict__ b1) {
  __shared__ float sRF[32][68];
  __shared__ float sW2[32][68];
  __shared__ float sW1[64][68];
  __shared__ float sO[64][68];
  bool isP = blockIdx.x >= 128;
  const float* rf = isP ? rfP : rfR;
  float* agg = isP ? aggP : aggR;
  float* u = isP ? uP : uR;
  int n0 = (blockIdx.x & 127) * 64;
  int t = threadIdx.x;
#pragma unroll
  for (int idx = 0; idx < 4; ++idx) {
    int q = t * 4 + idx * 1024;
    *reinterpret_cast<float4*>(&sW1[q >> 6][q & 63]) = *reinterpret_cast<const float4*>(W1 + q);
  }
#pragma unroll
  for (int idx = 0; idx < 2; ++idx) {
    int q = t * 4 + idx * 1024;
    *reinterpret_cast<float4*>(&sW2[q >> 6][q & 63]) = *reinterpret_cast<const float4*>(Ws2 + q);
    int r = q >> 5, kk = q & 31;
    float4 v = *reinterpret_cast<const float4*>(rf + (size_t)(n0 + r) * 32 + kk);
    sRF[kk][r] = v.x; sRF[kk + 1][r] = v.y; sRF[kk + 2][r] = v.z; sRF[kk + 3][r] = v.w;
  }
  __syncthreads();
  int tn = (t & 15) * 4, tj = (t >> 4) * 4;
  float acc[4][4] = {};
#pragma unroll 8
  for (int k = 0; k < 32; ++k) {
    float4 a = *reinterpret_cast<const float4*>(&sRF[k][tn]);
    float4 b = *reinterpret_cast<const float4*>(&sW2[k][tj]);
    acc[0][0] = fmaf(a.x, b.x, acc[0][0]); acc[0][1] = fmaf(a.x, b.y, acc[0][1]);
    acc[0][2] = fmaf(a.x, b.z, acc[0][2]); acc[0][3] = fmaf(a.x, b.w, acc[0][3]);
    acc[1][0] = fmaf(a.y, b.x, acc[1][0]); acc[1][1] = fmaf(a.y, b.y, acc[1][1]);
    acc[1][2] = fmaf(a.y, b.z, acc[1][2]); acc[1][3] = fmaf(a.y, b.w, acc[1][3]);
    acc[2][0] = fmaf(a.z, b.x, acc[2][0]); acc[2][1] = fmaf(a.z, b.y, acc[2][1]);
    acc[2][2] = fmaf(a.z, b.z, acc[2][2]); acc[2][3] = fmaf(a.z, b.w, acc[2][3]);
    acc[3][0] = fmaf(a.w, b.x, acc[3][0]); acc[3][1] = fmaf(a.w, b.y, acc[3][1]);
    acc[3][2] = fmaf(a.w, b.z, acc[3][2]); acc[3][3] = fmaf(a.w, b.w, acc[3][3]);
  }
  float4 bg = *reinterpret_cast<const float4*>(g2b + tj);
  float4 z4 = make_float4(0.f, 0.f, 0.f, 0.f);
#pragma unroll
  for (int i = 0; i < 4; ++i) {
    int n = n0 + tn + i;
    float4 g = *reinterpret_cast<const float4*>(&agg[(size_t)n * 64 + tj]);
    *reinterpret_cast<float4*>(&agg[(size_t)n * 64 + tj]) = z4;  // re-arm for next iter
    sO[tj + 0][tn + i] = fmaxf(acc[i][0] + g.x + bg.x, 0.f);
    sO[tj + 1][tn + i] = fmaxf(acc[i][1] + g.y + bg.y, 0.f);
    sO[tj + 2][tn + i] = fmaxf(acc[i][2] + g.z + bg.z, 0.f);
    sO[tj + 3][tn + i] = fmaxf(acc[i][3] + g.w + bg.w, 0.f);
  }
  __syncthreads();
  float acc2[4][4] = {};
#pragma unroll 8
  for (int k = 0; k < 64; ++k) {
    float4 a = *reinterpret_cast<const float4*>(&sO[k][tn]);
    float4 b = *reinterpret_cast<const float4*>(&sW1[k][tj]);
    acc2[0][0] = fmaf(a.x, b.x, acc2[0][0]); acc2[0][1] = fmaf(a.x, b.y, acc2[0][1]);
    acc2[0][2] = fmaf(a.x, b.z, acc2[0][2]); acc2[0][3] = fmaf(a.x, b.w, acc2[0][3]);
    acc2[1][0] = fmaf(a.y, b.x, acc2[1][0]); acc2[1][1] = fmaf(a.y, b.y, acc2[1][1]);
    acc2[1][2] = fmaf(a.y, b.z, acc2[1][2]); acc2[1][3] = fmaf(a.y, b.w, acc2[1][3]);
    acc2[2][0] = fmaf(a.z, b.x, acc2[2][0]); acc2[2][1] = fmaf(a.z, b.y, acc2[2][1]);
    acc2[2][2] = fmaf(a.z, b.z, acc2[2][2]); acc2[2][3] = fmaf(a.z, b.w, acc2[2][3]);
    acc2[3][0] = fmaf(a.w, b.x, acc2[3][0]); acc2[3][1] = fmaf(a.w, b.y, acc2[3][1]);
    acc2[3][2] = fmaf(a.w, b.z, acc2[3][2]); acc2[3][3] = fmaf(a.w, b.w, acc2[3][3]);
  }
  float4 b1v = make_float4(0.f, 0.f, 0.f, 0.f);
  if (!isP) b1v = *reinterpret_cast<const float4*>(b1 + tj);
#pragma unroll
  for (int i = 0; i < 4; ++i) {
    int n = n0 + tn + i;
    float4 o;
    o.x = acc2[i][0] + b1v.x; o.y = acc2[i][1] + b1v.y;
    o.z = acc2[i][2] + b1v.z; o.w = acc2[i][3] + b1v.w;
    *reinterpret_cast<float4*>(&u[(size_t)n * 64 + tj]) = o;
  }
}

// ====== upd_soft: Mhat += pairwise MLP; fused row softmax -> (Msoft | final out);
//        optional RNG for next iteration. 512 blocks. ======
__global__ __launch_bounds__(256) void upd_soft(
    const float* __restrict__ uR, const float* __restrict__ uP,
    const float* __restrict__ W2, const float* __restrict__ b2p,
    float* __restrict__ Mhat, float* __restrict__ softDst,
    int writeMhat, float* __restrict__ rfr, int doRng,
    unsigned fk0, unsigned fk1) {
  __shared__ float sur[16][66];
  __shared__ float sup[128][66];
  __shared__ float sw2[64];
  int gid = blockIdx.x, t = threadIdx.x;
  int b = gid >> 3, r0 = (gid & 7) * 16;
  const float* urG = uR + ((size_t)(b * 128 + r0)) * 64;
  {
    int q = t * 4; int r = q >> 6, d = q & 63;
    float4 v = *reinterpret_cast<const float4*>(urG + q);
    sur[r][d] = v.x; sur[r][d + 1] = v.y; sur[r][d + 2] = v.z; sur[r][d + 3] = v.w;
  }
  const float* upG = uP + (size_t)b * 128 * 64;
#pragma unroll
  for (int rep = 0; rep < 8; ++rep) {
    int q = (rep * 256 + t) * 4; int p = q >> 6, d = q & 63;
    float4 v = *reinterpret_cast<const float4*>(upG + q);
    sup[p][d] = v.x; sup[p][d + 1] = v.y; sup[p][d + 2] = v.z; sup[p][d + 3] = v.w;
  }
  if (t < 64) sw2[t] = W2[t];
  __syncthreads();
  int tx = t & 31, ty = t >> 5;
  float acc[2][4] = {};
  for (int j = 0; j < 64; ++j) {
    float w2v = sw2[j];
    float a0 = sur[ty][j], a1 = sur[ty + 8][j];
    float q0 = sup[tx][j], q1 = sup[tx + 32][j], q2 = sup[tx + 64][j], q3 = sup[tx + 96][j];
    acc[0][0] = fmaf(fmaxf(a0 - q0, 0.f), w2v, acc[0][0]);
    acc[0][1] = fmaf(fmaxf(a0 - q1, 0.f), w2v, acc[0][1]);
    acc[0][2] = fmaf(fmaxf(a0 - q2, 0.f), w2v, acc[0][2]);
    acc[0][3] = fmaf(fmaxf(a0 - q3, 0.f), w2v, acc[0][3]);
    acc[1][0] = fmaf(fmaxf(a1 - q0, 0.f), w2v, acc[1][0]);
    acc[1][1] = fmaf(fmaxf(a1 - q1, 0.f), w2v, acc[1][1]);
    acc[1][2] = fmaf(fmaxf(a1 - q2, 0.f), w2v, acc[1][2]);
    acc[1][3] = fmaf(fmaxf(a1 - q3, 0.f), w2v, acc[1][3]);
  }
  float b2v = b2p[0];
#pragma unroll
  for (int ii = 0; ii < 2; ++ii) {
    int r = r0 + ty + 8 * ii;
    float* mrow = Mhat + ((size_t)(b * 128 + r)) * 128;
    float m0 = mrow[tx] + acc[ii][0] + b2v;
    float m1 = mrow[tx + 32] + acc[ii][1] + b2v;
    float m2 = mrow[tx + 64] + acc[ii][2] + b2v;
    float m3 = mrow[tx + 96] + acc[ii][3] + b2v;
    if (writeMhat) {
      mrow[tx] = m0; mrow[tx + 32] = m1; mrow[tx + 64] = m2; mrow[tx + 96] = m3;
    }
    float mx = redmax32(fmaxf(fmaxf(m0, m1), fmaxf(m2, m3)));
    float e0 = __expf(m0 - mx), e1 = __expf(m1 - mx);
    float e2 = __expf(m2 - mx), e3 = __expf(m3 - mx);
    float inv = 1.0f / redsum32(e0 + e1 + e2 + e3);
    float* srow = softDst + ((size_t)(b * 128 + r)) * 128;
    srow[tx] = e0 * inv; srow[tx + 32] = e1 * inv;
    srow[tx + 64] = e2 * inv; srow[tx + 96] = e3 * inv;
  }
  if (doRng) {
    int gtid = (gid << 8) + t;
#pragma unroll
    for (int q = 0; q < 2; ++q) {
      unsigned i = (unsigned)gtid + (unsigned)q * 131072u;
      unsigned a0 = 0u, a1 = i;
      tf2x32(fk0, fk1, a0, a1);
      rfr[i] = bits_to_normal(a0 ^ a1);
    }
  }
}

extern "C" void kernel_launch(void* const* d_in, const int* in_sizes, int n_in,
                              void* d_out, int out_size, void* d_ws, size_t ws_size,
                              hipStream_t stream) {
  (void)in_sizes; (void)n_in; (void)out_size; (void)ws_size;
  const float* x_r  = (const float*)d_in[0];
  const int*   ei_r = (const int*)d_in[1];
  const float* ef_r = (const float*)d_in[2];
  const float* x_p  = (const float*)d_in[3];
  const int*   ei_p = (const int*)d_in[4];
  const float* ef_p = (const float*)d_in[5];
  const float* g1_Ws = (const float*)d_in[8];
  const float* g1_Wm = (const float*)d_in[9];
  const float* g1_We = (const float*)d_in[10];
  const float* g1_b  = (const float*)d_in[11];
  const float* g2_Ws = (const float*)d_in[12];
  const float* g2_Wm = (const float*)d_in[13];
  const float* g2_We = (const float*)d_in[14];
  const float* g2_b  = (const float*)d_in[15];
  const float* W1 = (const float*)d_in[16];
  const float* b1 = (const float*)d_in[17];
  const float* W2 = (const float*)d_in[18];
  const float* b2 = (const float*)d_in[19];
  float* out = (float*)d_out;

  float* ws = (float*)d_ws;
  float* h_r   = ws;                 // 524288
  float* h_p   = h_r + 524288;       // 524288
  float* Mhat  = h_p + 524288;       // 1048576
  float* Msoft = Mhat + 1048576;     // 1048576
  float* rfr   = Msoft + 1048576;    // 262144
  float* rfp   = rfr + 262144;       // 262144
  float* u_r   = rfp + 262144;       // 524288
  float* u_p   = u_r + 524288;       // 524288
  float* agg_r = u_p + 524288;       // 524288
  float* agg_p = agg_r + 524288;     // 524288 (contiguous with agg_r for zeroing)
  int* ib      = (int*)(agg_p + 524288);
  int* cnt_r  = ib;                  // 8192 (zeroed)
  int* cnt_p  = cnt_r + 8192;        // 8192 (zeroed)
  int* off_r  = cnt_p + 8192;        // 8192
  int* off_p  = off_r + 8192;        // 8192
  int* rp_r   = off_p + 8192;        // 8193
  int* rp_p   = rp_r + 8193;         // 8193
  int* perm_r = rp_p + 8193;         // 65536
  int* perm_p = perm_r + 65536;      // 65536
  int* srcs_r = perm_p + 65536;      // 65536
  int* srcs_p = srcs_r + 65536;      // 65536
  int* dsts_r = srcs_p + 65536;      // 65536
  int* dsts_p = dsts_r + 65536;      // 65536

  // folded keys for the 3 iterations (host-side, deterministic)
  unsigned fk0[3], fk1[3];
  for (int it = 0; it < 3; ++it) {
    unsigned a = 0u, c = (unsigned)it;
    tf2x32(0u, 42u, a, c);
    fk0[it] = a; fk1[it] = c;
  }

  // ---- CSR build (multi-block) + agg zeroing fused into hist ----
  hipMemsetAsync(cnt_r, 0, 2 * 8192 * sizeof(int), stream);
  hist_kern<<<512, 256, 0, stream>>>(ei_r, ei_p, cnt_r, cnt_p, agg_r);
  scan_kern<<<2, 256, 0, stream>>>(cnt_r, rp_r, off_r, cnt_p, rp_p, off_p);
  scatter_kern<<<512, 256, 0, stream>>>(ei_r, ei_p, off_r, off_p,
                                        perm_r, perm_p, srcs_r, srcs_p,
                                        dsts_r, dsts_p);

  // ---- gnn1 (msg GEMM now scatters directly into agg via segment-reduced atomics) ----
  msg_gemm<64><<<2048, 256, 0, stream>>>(x_r, ef_r, srcs_r, perm_r, dsts_r, agg_r,
                                         x_p, ef_p, srcs_p, perm_p, dsts_p, agg_p,
                                         g1_Wm, g1_We);
  node1_gemm<<<256, 256, 0, stream>>>(x_r, agg_r, h_r, x_p, agg_p, h_p, g1_Ws, g1_b);
  mhat_soft<<<512, 256, 0, stream>>>(h_r, h_p, Mhat, Msoft, out, rfr, fk0[0], fk1[0]);

  for (int it = 0; it < 3; ++it) {
    rfp_kern<<<512, 256, 0, stream>>>(Msoft, rfr, rfp);
    msg_gemm<32><<<2048, 256, 0, stream>>>(rfr, ef_r, srcs_r, perm_r, dsts_r, agg_r,
                                           rfp, ef_p, srcs_p, perm_p, dsts_p, agg_p,
                                           g2_Wm, g2_We);
    node2u_gemm<<<256, 256, 0, stream>>>(rfr, agg_r, u_r, rfp, agg_p, u_p,
                                         g2_Ws, g2_b, W1, b1);
    int last = (it == 2);
    upd_soft<<<512, 256, 0, stream>>>(u_r, u_p, W2, b2, Mhat,
                                      last ? (out + 1048576) : Msoft,
                                      /*writeMhat=*/!last,
                                      rfr, /*doRng=*/!last,
                                      fk0[it < 2 ? it + 1 : 0], fk1[it < 2 ? it + 1 : 0]);
  }
}